// Round 1
// baseline (2611.276 us; speedup 1.0000x reference)
//
#include <hip/hip_runtime.h>
#include <hip/hip_bf16.h>
#include <math.h>

#define DEV __device__ __forceinline__

DEV float gelu_exact(float x){ return 0.5f*x*(1.0f + erff(x*0.70710678118654752f)); }

// ---------------- K1: conv1(1->16,3x3,pad1) + maxpool2 + gelu ----------------
// grid (8,8,32) block 256; out h1 (32,16,128,128)
__global__ __launch_bounds__(256) void k_conv1(const float* __restrict__ x,
    const float* __restrict__ w1, const float* __restrict__ b1,
    float* __restrict__ h1)
{
  __shared__ float tile[34*35];
  __shared__ float wsm[144];
  __shared__ float bsm[16];
  const int b = blockIdx.z;
  const int r0 = blockIdx.y*32, c0 = blockIdx.x*32;   // unpooled origin (256-res)
  const float* xp = x + (size_t)b*65536;
  for(int i=threadIdx.x;i<34*34;i+=256){
    int r=i/34, c=i-r*34;
    int gr=r0+r-1, gc=c0+c-1;
    float v=0.f;
    if(gr>=0 && gr<256 && gc>=0 && gc<256) v = xp[gr*256+gc];
    tile[r*35+c]=v;
  }
  if(threadIdx.x<144) wsm[threadIdx.x]=w1[threadIdx.x];
  if(threadIdx.x<16)  bsm[threadIdx.x]=b1[threadIdx.x];
  __syncthreads();
  const int tx=threadIdx.x&15, ty=threadIdx.x>>4;
  float in[4][4];
  #pragma unroll
  for(int r=0;r<4;r++)
    #pragma unroll
    for(int c=0;c<4;c++) in[r][c]=tile[(2*ty+r)*35 + 2*tx + c];
  const int py = blockIdx.y*16+ty, px = blockIdx.x*16+tx;
  float* op = h1 + ((size_t)b*16)*16384 + py*128 + px;
  #pragma unroll
  for(int ch=0;ch<16;ch++){
    float m=-1e30f;
    #pragma unroll
    for(int pr=0;pr<2;pr++)
      #pragma unroll
      for(int pc=0;pc<2;pc++){
        float a=0.f;
        #pragma unroll
        for(int ky=0;ky<3;ky++)
          #pragma unroll
          for(int kx=0;kx<3;kx++)
            a = fmaf(in[pr+ky][pc+kx], wsm[ch*9+ky*3+kx], a);
        m = fmaxf(m,a);
      }
    op[(size_t)ch*16384] = gelu_exact(m + bsm[ch]);
  }
}

// ---------------- K2: conv2(16->32,3x3,pad1) + maxpool2 ----------------
// grid (8,8,32) block 512; out h2 (32,32,64,64)
__global__ __launch_bounds__(512) void k_conv2(const float* __restrict__ h1,
    const float* __restrict__ w2, const float* __restrict__ b2,
    float* __restrict__ h2)
{
  __shared__ float tile[16*342];   // [ic][18][19]
  __shared__ float wsm[4608];      // (32,16,3,3)
  __shared__ float bsm[32];
  const int b=blockIdx.z;
  const int r0=blockIdx.y*16, c0=blockIdx.x*16;  // unpooled origin (128-res)
  const float* hp = h1 + (size_t)b*16*16384;
  for(int i=threadIdx.x;i<16*324;i+=512){
    int ic=i/324, rem=i-ic*324, r=rem/18, c=rem-r*18;
    int gr=r0+r-1, gc=c0+c-1;
    float v=0.f;
    if(gr>=0&&gr<128&&gc>=0&&gc<128) v=hp[(size_t)ic*16384+gr*128+gc];
    tile[ic*342+r*19+c]=v;
  }
  for(int i=threadIdx.x;i<4608;i+=512) wsm[i]=w2[i];
  if(threadIdx.x<32) bsm[threadIdx.x]=b2[threadIdx.x];
  __syncthreads();
  const int pos=threadIdx.x&63, ocg=threadIdx.x>>6;  // wave-uniform ocg
  const int pyl=pos>>3, pxl=pos&7;
  float acc[4][4];
  #pragma unroll
  for(int i=0;i<4;i++)
    #pragma unroll
    for(int j=0;j<4;j++) acc[i][j]=0.f;
  #pragma unroll
  for(int ic=0;ic<16;ic++){
    float in[4][4];
    #pragma unroll
    for(int r=0;r<4;r++)
      #pragma unroll
      for(int c=0;c<4;c++)
        in[r][c]=tile[ic*342+(2*pyl+r)*19+2*pxl+c];
    #pragma unroll
    for(int o=0;o<4;o++){
      const int oc=ocg*4+o;
      const float* wp=&wsm[(oc*16+ic)*9];
      #pragma unroll
      for(int pr=0;pr<2;pr++)
        #pragma unroll
        for(int pc=0;pc<2;pc++){
          float s=acc[o][pr*2+pc];
          #pragma unroll
          for(int ky=0;ky<3;ky++)
            #pragma unroll
            for(int kx=0;kx<3;kx++)
              s=fmaf(in[pr+ky][pc+kx], wp[ky*3+kx], s);
          acc[o][pr*2+pc]=s;
        }
    }
  }
  const int py=blockIdx.y*8+pyl, px=blockIdx.x*8+pxl;
  #pragma unroll
  for(int o=0;o<4;o++){
    const int oc=ocg*4+o;
    float m=fmaxf(fmaxf(acc[o][0],acc[o][1]),fmaxf(acc[o][2],acc[o][3]));
    h2[(((size_t)b*32+oc)*64+py)*64+px]=m+bsm[oc];
  }
}

// ---------------- K2b: groupnorm stats (deterministic, f64) ----------------
// grid 128 (= b*4+g), block 256; stats: mean[128], rstd[128]
__global__ __launch_bounds__(256) void k_stats(const float* __restrict__ h2,
                                               float* __restrict__ stats)
{
  const int b=blockIdx.x>>2, g=blockIdx.x&3;
  const float* p = h2 + ((size_t)b*32 + g*8)*4096;
  double s=0.0, s2=0.0;
  for(int i=threadIdx.x;i<32768;i+=256){ float v=p[i]; s+=v; s2+=(double)v*v; }
  __shared__ double rs[256], rs2[256];
  rs[threadIdx.x]=s; rs2[threadIdx.x]=s2; __syncthreads();
  for(int st=128;st>0;st>>=1){
    if(threadIdx.x<st){ rs[threadIdx.x]+=rs[threadIdx.x+st]; rs2[threadIdx.x]+=rs2[threadIdx.x+st]; }
    __syncthreads();
  }
  if(threadIdx.x==0){
    double mu=rs[0]/32768.0;
    double var=rs2[0]/32768.0 - mu*mu;
    stats[blockIdx.x]=(float)mu;
    stats[128+blockIdx.x]=(float)(1.0/sqrt(var+1e-5));
  }
}

// ---------------- K3: groupnorm-apply + 1x1 conv + residual LFQ ----------------
// grid 512 (= b*16 + rowgrp), block 256 (1 token/thread, 4 rows x 64 cols)
__global__ __launch_bounds__(256) void k_lfq(const float* __restrict__ h2,
    const float* __restrict__ stats, const float* __restrict__ w3, const float* __restrict__ b3,
    float* __restrict__ qout, float* __restrict__ idxout,
    float* __restrict__ avgp, float* __restrict__ ec)
{
  __shared__ float tab[256*33];   // per-token lo[16]|hi[16], stride 33 (bank spread)
  __shared__ float w3s[256];
  __shared__ float b3s[8];
  const int blk=blockIdx.x;
  const int b=blk>>4;
  const int t=threadIdx.x;
  const int h=(blk&15)*4 + (t>>6);
  const int w=t&63;
  w3s[t]=w3[t];
  if(t<8) b3s[t]=b3[t];
  __syncthreads();
  float mu[4], rs[4];
  #pragma unroll
  for(int g=0;g<4;g++){ mu[g]=stats[b*4+g]; rs[g]=stats[128+b*4+g]; }
  const float* hp = h2 + (size_t)b*131072 + h*64 + w;
  float z[8];
  #pragma unroll
  for(int d=0;d<8;d++) z[d]=b3s[d];
  #pragma unroll
  for(int c=0;c<32;c++){
    float xn=(hp[(size_t)c*4096]-mu[c>>3])*rs[c>>3];
    #pragma unroll
    for(int d=0;d<8;d++) z[d]=fmaf(xn, w3s[d*32+c], z[d]);
  }
  float r[8], qsum[8];
  #pragma unroll
  for(int d=0;d<8;d++){ r[d]=z[d]; qsum[d]=0.f; }
  float entk[2], comk[2];
  #pragma unroll
  for(int k=0;k<2;k++){
    int idx=0; float ent=0.f, com=0.f;
    float pb0[8], pb1[8];
    #pragma unroll
    for(int d=0;d<8;d++){
      float rv=r[d];
      bool pos = rv>0.f;
      float sgn = pos?1.f:-1.f;
      idx |= (pos?1:0)<<d;
      float dd=rv-sgn; com=fmaf(dd,dd,com);
      // softmax over the +-1 product codebook factorizes into 8 Bernoulli bits:
      float a=400.f*fabsf(rv);
      float e=expf(-a);
      float inv=1.f/(1.f+e);
      ent += log1pf(e) + a*e*inv;     // per-bit entropy, exact closed form
      float pm=inv, pq=e*inv;         // P(bit matches sign), P(mismatch)
      pb1[d]=pos?pm:pq;
      pb0[d]=pos?pq:pm;
      qsum[d]+=sgn;
      r[d]=rv-sgn;
    }
    // split product tables: lo over bits 0..3, hi over bits 4..7 (all static idx)
    float lo[16], hi[16];
    lo[0]=pb0[0]; lo[1]=pb1[0];
    lo[2]=lo[0]*pb1[1]; lo[3]=lo[1]*pb1[1]; lo[0]*=pb0[1]; lo[1]*=pb0[1];
    lo[4]=lo[0]*pb1[2]; lo[5]=lo[1]*pb1[2]; lo[6]=lo[2]*pb1[2]; lo[7]=lo[3]*pb1[2];
    lo[0]*=pb0[2]; lo[1]*=pb0[2]; lo[2]*=pb0[2]; lo[3]*=pb0[2];
    lo[8]=lo[0]*pb1[3]; lo[9]=lo[1]*pb1[3]; lo[10]=lo[2]*pb1[3]; lo[11]=lo[3]*pb1[3];
    lo[12]=lo[4]*pb1[3]; lo[13]=lo[5]*pb1[3]; lo[14]=lo[6]*pb1[3]; lo[15]=lo[7]*pb1[3];
    lo[0]*=pb0[3]; lo[1]*=pb0[3]; lo[2]*=pb0[3]; lo[3]*=pb0[3];
    lo[4]*=pb0[3]; lo[5]*=pb0[3]; lo[6]*=pb0[3]; lo[7]*=pb0[3];
    hi[0]=pb0[4]; hi[1]=pb1[4];
    hi[2]=hi[0]*pb1[5]; hi[3]=hi[1]*pb1[5]; hi[0]*=pb0[5]; hi[1]*=pb0[5];
    hi[4]=hi[0]*pb1[6]; hi[5]=hi[1]*pb1[6]; hi[6]=hi[2]*pb1[6]; hi[7]=hi[3]*pb1[6];
    hi[0]*=pb0[6]; hi[1]*=pb0[6]; hi[2]*=pb0[6]; hi[3]*=pb0[6];
    hi[8]=hi[0]*pb1[7]; hi[9]=hi[1]*pb1[7]; hi[10]=hi[2]*pb1[7]; hi[11]=hi[3]*pb1[7];
    hi[12]=hi[4]*pb1[7]; hi[13]=hi[5]*pb1[7]; hi[14]=hi[6]*pb1[7]; hi[15]=hi[7]*pb1[7];
    hi[0]*=pb0[7]; hi[1]*=pb0[7]; hi[2]*=pb0[7]; hi[3]*=pb0[7];
    hi[4]*=pb0[7]; hi[5]*=pb0[7]; hi[6]*=pb0[7]; hi[7]*=pb0[7];
    #pragma unroll
    for(int m=0;m<16;m++){ tab[t*33+m]=lo[m]; tab[t*33+16+m]=hi[m]; }
    __syncthreads();
    // phase 2: code-parallel avg_prob partial (thread t owns code t)
    float accp=0.f;
    const int jl=t&15, jh=t>>4;
    for(int tt=0;tt<256;tt++)
      accp=fmaf(tab[tt*33+jl], tab[tt*33+16+jh], accp);
    avgp[((size_t)k*512+blk)*256+t]=accp;
    __syncthreads();
    entk[k]=ent; comk[k]=com;
    idxout[((size_t)(b*64+h)*64+w)*2+k]=(float)idx;
  }
  #pragma unroll
  for(int d=0;d<8;d++)
    qout[(((size_t)b*8+d)*64+h)*64+w]=qsum[d];
  // block-reduce entropy/commit partials (reuse tab)
  tab[t]=entk[0]; tab[256+t]=entk[1]; tab[512+t]=comk[0]; tab[768+t]=comk[1];
  __syncthreads();
  for(int st=128;st>0;st>>=1){
    if(t<st){ tab[t]+=tab[t+st]; tab[256+t]+=tab[256+t+st];
              tab[512+t]+=tab[512+t+st]; tab[768+t]+=tab[768+t+st]; }
    __syncthreads();
  }
  if(t==0){ ec[blk*4+0]=tab[0]; ec[blk*4+1]=tab[256]; ec[blk*4+2]=tab[512]; ec[blk*4+3]=tab[768]; }
}

// ---------------- K3b: final aux reduction (1 block, deterministic, f64) ----------------
__global__ __launch_bounds__(256) void k_final(const float* __restrict__ avgp,
    const float* __restrict__ ec, float* __restrict__ auxout)
{
  __shared__ double red[256];
  const int t=threadIdx.x;
  double cb=0.0;
  #pragma unroll
  for(int k=0;k<2;k++){
    double s=0.0;
    for(int blk=0;blk<512;blk++) s += (double)avgp[((size_t)k*512+blk)*256+t];
    double ap = s*(1.0/131072.0);
    cb += -(ap*log(ap+1e-10));
  }
  red[t]=cb; __syncthreads();
  for(int st=128;st>0;st>>=1){ if(t<st) red[t]+=red[t+st]; __syncthreads(); }
  double CB=red[0]; __syncthreads();
  double e=0.0,c=0.0;
  for(int blk=t;blk<512;blk+=256){
    e += (double)ec[blk*4+0]+(double)ec[blk*4+1];
    c += (double)ec[blk*4+2]+(double)ec[blk*4+3];
  }
  red[t]=e; __syncthreads();
  for(int st=128;st>0;st>>=1){ if(t<st) red[t]+=red[t+st]; __syncthreads(); }
  double E=red[0]; __syncthreads();
  red[t]=c; __syncthreads();
  for(int st=128;st>0;st>>=1){ if(t<st) red[t]+=red[t+st]; __syncthreads(); }
  if(t==0){
    double C=red[0];
    double aux = 0.1*(E*(1.0/131072.0) - CB) + C*(1.0/1048576.0);
    auxout[0]=(float)aux;
  }
}

// ---------------- K4: decoder conv d1 (8->32, 3x3, pad1) on 64x64 ----------------
// grid (4,4,32) block 256
__global__ __launch_bounds__(256) void k_dec1(const float* __restrict__ q,
    const float* __restrict__ d1, const float* __restrict__ db1, float* __restrict__ out1)
{
  __shared__ float tile[8*342];   // [ic][18][19]
  __shared__ float wsm[2304];
  __shared__ float bsm[32];
  const int b=blockIdx.z, r0=blockIdx.y*16, c0=blockIdx.x*16;
  const float* qp = q + (size_t)b*8*4096;
  for(int i=threadIdx.x;i<8*324;i+=256){
    int ic=i/324, rem=i-ic*324, r=rem/18, c=rem-r*18;
    int gr=r0+r-1, gc=c0+c-1;
    float v=0.f;
    if(gr>=0&&gr<64&&gc>=0&&gc<64) v=qp[ic*4096+gr*64+gc];
    tile[ic*342+r*19+c]=v;
  }
  for(int i=threadIdx.x;i<2304;i+=256) wsm[i]=d1[i];
  if(threadIdx.x<32) bsm[threadIdx.x]=db1[threadIdx.x];
  __syncthreads();
  const int tx=threadIdx.x&15, ty=threadIdx.x>>4;
  float acc[32];
  #pragma unroll
  for(int o=0;o<32;o++) acc[o]=bsm[o];
  #pragma unroll
  for(int ic=0;ic<8;ic++){
    float v[9];
    #pragma unroll
    for(int ky=0;ky<3;ky++)
      #pragma unroll
      for(int kx=0;kx<3;kx++)
        v[ky*3+kx]=tile[ic*342+(ty+ky)*19+tx+kx];
    #pragma unroll
    for(int o=0;o<32;o++){
      const float* wp=&wsm[(o*8+ic)*9];
      float s=acc[o];
      #pragma unroll
      for(int kk=0;kk<9;kk++) s=fmaf(v[kk],wp[kk],s);
      acc[o]=s;
    }
  }
  float* op = out1 + (size_t)b*32*4096 + (r0+ty)*64 + (c0+tx);
  #pragma unroll
  for(int o=0;o<32;o++) op[(size_t)o*4096]=acc[o];
}

// ---------------- K5: upsample2 + conv d2 (32->16,3x3,pad1) + gelu, at 128-res ----------------
// parity-combined 2x2 weights; grid (8,8,32) block 256
__global__ __launch_bounds__(256) void k_dec2(const float* __restrict__ out1,
    const float* __restrict__ d2, const float* __restrict__ db2, float* __restrict__ out2)
{
  __shared__ float tile[32*110];   // [ic][10][11] src at 64-res
  __shared__ float4 wp4[2048];     // [(ic*16+oc)*4+par]
  __shared__ float bsm[16];
  const int b=blockIdx.z, y0=blockIdx.y*16, x0=blockIdx.x*16;
  const int sy0=(y0>>1)-1, sx0=(x0>>1)-1;
  const float* sp = out1 + (size_t)b*32*4096;
  for(int i=threadIdx.x;i<3200;i+=256){
    int ic=i/100, rem=i-ic*100, r=rem/10, c=rem-r*10;
    int gr=sy0+r, gc=sx0+c;
    float v=0.f;
    if(gr>=0&&gr<64&&gc>=0&&gc<64) v=sp[ic*4096+gr*64+gc];
    tile[ic*110+r*11+c]=v;
  }
  for(int i=threadIdx.x;i<2048;i+=256){
    int par=i&3, oc=(i>>2)&15, ic=i>>6;
    int py=par>>1, px=par&1;
    const float* wg = d2 + ((size_t)oc*32+ic)*9;
    float a00=0.f,a01=0.f,a10=0.f,a11=0.f;
    #pragma unroll
    for(int ky=0;ky<3;ky++){
      int sy = py ? (ky>>1) : ((ky>0)?1:0);
      #pragma unroll
      for(int kx=0;kx<3;kx++){
        int sx = px ? (kx>>1) : ((kx>0)?1:0);
        float wv=wg[ky*3+kx];
        if(sy==0){ if(sx==0)a00+=wv; else a01+=wv; }
        else     { if(sx==0)a10+=wv; else a11+=wv; }
      }
    }
    wp4[i]=make_float4(a00,a01,a10,a11);
  }
  if(threadIdx.x<16) bsm[threadIdx.x]=db2[threadIdx.x];
  __syncthreads();
  const int tx=threadIdx.x&15, ty=threadIdx.x>>4;
  const int par=((ty&1)<<1)|(tx&1);
  const int byl=((ty-1)>>1)+1, bxl=((tx-1)>>1)+1;
  float acc[16];
  #pragma unroll
  for(int o=0;o<16;o++) acc[o]=bsm[o];
  #pragma unroll
  for(int ic=0;ic<32;ic++){
    const float* tp=&tile[ic*110+byl*11+bxl];
    float s00=tp[0], s01=tp[1], s10=tp[11], s11=tp[12];
    #pragma unroll
    for(int o=0;o<16;o++){
      float4 wv=wp4[(ic*16+o)*4+par];
      acc[o]=fmaf(s00,wv.x,fmaf(s01,wv.y,fmaf(s10,wv.z,fmaf(s11,wv.w,acc[o]))));
    }
  }
  float* op = out2 + (size_t)b*16*16384 + (y0+ty)*128 + (x0+tx);
  #pragma unroll
  for(int o=0;o<16;o++) op[(size_t)o*16384]=gelu_exact(acc[o]);
}

// ---------------- K6: upsample2 + conv d3 (16->1,3x3,pad1) + clip, at 256-res ----------------
// grid (8,8,32) block 256, 4 px/thread (32x32 tile)
__global__ __launch_bounds__(256) void k_dec3(const float* __restrict__ out2,
    const float* __restrict__ d3, const float* __restrict__ db3, float* __restrict__ y)
{
  __shared__ float tile[16*342];   // [ic][18][19] src at 128-res
  __shared__ float4 wp4[64];       // [ic*4+par]
  const int b=blockIdx.z, y0=blockIdx.y*32, x0=blockIdx.x*32;
  const int sy0=(y0>>1)-1, sx0=(x0>>1)-1;
  const float* sp = out2 + (size_t)b*16*16384;
  for(int i=threadIdx.x;i<16*324;i+=256){
    int ic=i/324, rem=i-ic*324, r=rem/18, c=rem-r*18;
    int gr=sy0+r, gc=sx0+c;
    float v=0.f;
    if(gr>=0&&gr<128&&gc>=0&&gc<128) v=sp[ic*16384+gr*128+gc];
    tile[ic*342+r*19+c]=v;
  }
  if(threadIdx.x<64){
    int ic=threadIdx.x>>2, par=threadIdx.x&3;
    int py=par>>1, px=par&1;
    const float* wg = d3 + ic*9;
    float a00=0.f,a01=0.f,a10=0.f,a11=0.f;
    #pragma unroll
    for(int ky=0;ky<3;ky++){
      int sy = py ? (ky>>1) : ((ky>0)?1:0);
      #pragma unroll
      for(int kx=0;kx<3;kx++){
        int sx = px ? (kx>>1) : ((kx>0)?1:0);
        float wv=wg[ky*3+kx];
        if(sy==0){ if(sx==0)a00+=wv; else a01+=wv; }
        else     { if(sx==0)a10+=wv; else a11+=wv; }
      }
    }
    wp4[threadIdx.x]=make_float4(a00,a01,a10,a11);
  }
  __syncthreads();
  const float bias=db3[0];
  #pragma unroll
  for(int pi=0;pi<4;pi++){
    int p=threadIdx.x+256*pi;
    int yy=p>>5, xx=p&31;
    int par=((yy&1)<<1)|(xx&1);
    int byl=((yy-1)>>1)+1, bxl=((xx-1)>>1)+1;
    float acc=bias;
    #pragma unroll
    for(int ic=0;ic<16;ic++){
      const float* tp=&tile[ic*342+byl*19+bxl];
      float4 wv=wp4[ic*4+par];
      acc=fmaf(tp[0],wv.x,fmaf(tp[1],wv.y,fmaf(tp[19],wv.z,fmaf(tp[20],wv.w,acc))));
    }
    acc=fminf(fmaxf(acc,-1.0f),1.0f);
    y[(size_t)b*65536 + (size_t)(y0+yy)*256 + (x0+xx)] = acc;
  }
}

extern "C" void kernel_launch(void* const* d_in, const int* in_sizes, int n_in,
                              void* d_out, int out_size, void* d_ws, size_t ws_size,
                              hipStream_t stream)
{
  const float* x  =(const float*)d_in[0];
  const float* w1 =(const float*)d_in[1];
  const float* b1 =(const float*)d_in[2];
  const float* w2 =(const float*)d_in[3];
  const float* b2 =(const float*)d_in[4];
  const float* w3 =(const float*)d_in[5];
  const float* b3 =(const float*)d_in[6];
  const float* d1 =(const float*)d_in[7];
  const float* db1=(const float*)d_in[8];
  const float* d2 =(const float*)d_in[9];
  const float* db2=(const float*)d_in[10];
  const float* d3 =(const float*)d_in[11];
  const float* db3=(const float*)d_in[12];
  float* out=(float*)d_out;
  float* ws =(float*)d_ws;
  // ws layout (floats): h1[8388608] h2[4194304] q[1048576] stats[256] avgp[262144] ec[2048]
  float* h1   = ws;
  float* h2   = ws + 8388608;
  float* qb   = ws + 12582912;
  float* st   = ws + 13631488;
  float* avgp = ws + 13631744;
  float* ec   = ws + 13893888;
  float* out1 = h2;   // reuse: h2pre dead after k_lfq
  float* out2 = h1;   // reuse: h1 dead after k_conv2

  k_conv1<<<dim3(8,8,32),256,0,stream>>>(x,w1,b1,h1);
  k_conv2<<<dim3(8,8,32),512,0,stream>>>(h1,w2,b2,h2);
  k_stats<<<dim3(128),256,0,stream>>>(h2,st);
  k_lfq  <<<dim3(512),256,0,stream>>>(h2,st,w3,b3,qb,out+2097152,avgp,ec);
  k_final<<<dim3(1),256,0,stream>>>(avgp,ec,out+2359296);
  k_dec1 <<<dim3(4,4,32),256,0,stream>>>(qb,d1,db1,out1);
  k_dec2 <<<dim3(8,8,32),256,0,stream>>>(out1,d2,db2,out2);
  k_dec3 <<<dim3(8,8,32),256,0,stream>>>(out2,d3,db3,out);
}

// Round 2
// 330.371 us; speedup vs baseline: 7.9041x; 7.9041x over previous
//
#include <hip/hip_runtime.h>
#include <hip/hip_bf16.h>
#include <math.h>

#define DEV __device__ __forceinline__

DEV float gelu_exact(float x){ return 0.5f*x*(1.0f + erff(x*0.70710678118654752f)); }

// ---------------- K1: conv1(1->16,3x3,pad1) + maxpool2 + gelu ----------------
// grid (8,8,32) block 256; out h1 (32,16,128,128)
__global__ __launch_bounds__(256) void k_conv1(const float* __restrict__ x,
    const float* __restrict__ w1, const float* __restrict__ b1,
    float* __restrict__ h1)
{
  __shared__ float tile[34*35];
  __shared__ float wsm[144];
  __shared__ float bsm[16];
  const int b = blockIdx.z;
  const int r0 = blockIdx.y*32, c0 = blockIdx.x*32;   // unpooled origin (256-res)
  const float* xp = x + (size_t)b*65536;
  for(int i=threadIdx.x;i<34*34;i+=256){
    int r=i/34, c=i-r*34;
    int gr=r0+r-1, gc=c0+c-1;
    float v=0.f;
    if(gr>=0 && gr<256 && gc>=0 && gc<256) v = xp[gr*256+gc];
    tile[r*35+c]=v;
  }
  if(threadIdx.x<144) wsm[threadIdx.x]=w1[threadIdx.x];
  if(threadIdx.x<16)  bsm[threadIdx.x]=b1[threadIdx.x];
  __syncthreads();
  const int tx=threadIdx.x&15, ty=threadIdx.x>>4;
  float in[4][4];
  #pragma unroll
  for(int r=0;r<4;r++)
    #pragma unroll
    for(int c=0;c<4;c++) in[r][c]=tile[(2*ty+r)*35 + 2*tx + c];
  const int py = blockIdx.y*16+ty, px = blockIdx.x*16+tx;
  float* op = h1 + ((size_t)b*16)*16384 + py*128 + px;
  #pragma unroll
  for(int ch=0;ch<16;ch++){
    float m=-1e30f;
    #pragma unroll
    for(int pr=0;pr<2;pr++)
      #pragma unroll
      for(int pc=0;pc<2;pc++){
        float a=0.f;
        #pragma unroll
        for(int ky=0;ky<3;ky++)
          #pragma unroll
          for(int kx=0;kx<3;kx++)
            a = fmaf(in[pr+ky][pc+kx], wsm[ch*9+ky*3+kx], a);
        m = fmaxf(m,a);
      }
    op[(size_t)ch*16384] = gelu_exact(m + bsm[ch]);
  }
}

// ---------------- K2: conv2(16->32,3x3,pad1) + maxpool2 ----------------
// grid (8,8,32) block 512; out h2 (32,32,64,64)
__global__ __launch_bounds__(512) void k_conv2(const float* __restrict__ h1,
    const float* __restrict__ w2, const float* __restrict__ b2,
    float* __restrict__ h2)
{
  __shared__ float tile[16*342];   // [ic][18][19]
  __shared__ float wsm[4608];      // (32,16,3,3)
  __shared__ float bsm[32];
  const int b=blockIdx.z;
  const int r0=blockIdx.y*16, c0=blockIdx.x*16;  // unpooled origin (128-res)
  const float* hp = h1 + (size_t)b*16*16384;
  for(int i=threadIdx.x;i<16*324;i+=512){
    int ic=i/324, rem=i-ic*324, r=rem/18, c=rem-r*18;
    int gr=r0+r-1, gc=c0+c-1;
    float v=0.f;
    if(gr>=0&&gr<128&&gc>=0&&gc<128) v=hp[(size_t)ic*16384+gr*128+gc];
    tile[ic*342+r*19+c]=v;
  }
  for(int i=threadIdx.x;i<4608;i+=512) wsm[i]=w2[i];
  if(threadIdx.x<32) bsm[threadIdx.x]=b2[threadIdx.x];
  __syncthreads();
  const int pos=threadIdx.x&63, ocg=threadIdx.x>>6;  // wave-uniform ocg
  const int pyl=pos>>3, pxl=pos&7;
  float acc[4][4];
  #pragma unroll
  for(int i=0;i<4;i++)
    #pragma unroll
    for(int j=0;j<4;j++) acc[i][j]=0.f;
  #pragma unroll 4
  for(int ic=0;ic<16;ic++){
    float in[4][4];
    #pragma unroll
    for(int r=0;r<4;r++)
      #pragma unroll
      for(int c=0;c<4;c++)
        in[r][c]=tile[ic*342+(2*pyl+r)*19+2*pxl+c];
    #pragma unroll
    for(int o=0;o<4;o++){
      const int oc=ocg*4+o;
      const float* wp=&wsm[(oc*16+ic)*9];
      #pragma unroll
      for(int pr=0;pr<2;pr++)
        #pragma unroll
        for(int pc=0;pc<2;pc++){
          float s=acc[o][pr*2+pc];
          #pragma unroll
          for(int ky=0;ky<3;ky++)
            #pragma unroll
            for(int kx=0;kx<3;kx++)
              s=fmaf(in[pr+ky][pc+kx], wp[ky*3+kx], s);
          acc[o][pr*2+pc]=s;
        }
    }
  }
  const int py=blockIdx.y*8+pyl, px=blockIdx.x*8+pxl;
  #pragma unroll
  for(int o=0;o<4;o++){
    const int oc=ocg*4+o;
    float m=fmaxf(fmaxf(acc[o][0],acc[o][1]),fmaxf(acc[o][2],acc[o][3]));
    h2[(((size_t)b*32+oc)*64+py)*64+px]=m+bsm[oc];
  }
}

// ---------------- K2b: groupnorm stats (deterministic, f64) ----------------
// grid 128 (= b*4+g), block 256; stats: mean[128], rstd[128]
__global__ __launch_bounds__(256) void k_stats(const float* __restrict__ h2,
                                               float* __restrict__ stats)
{
  const int b=blockIdx.x>>2, g=blockIdx.x&3;
  const float* p = h2 + ((size_t)b*32 + g*8)*4096;
  double s=0.0, s2=0.0;
  for(int i=threadIdx.x;i<32768;i+=256){ float v=p[i]; s+=v; s2+=(double)v*v; }
  __shared__ double rs[256], rs2[256];
  rs[threadIdx.x]=s; rs2[threadIdx.x]=s2; __syncthreads();
  for(int st=128;st>0;st>>=1){
    if(threadIdx.x<st){ rs[threadIdx.x]+=rs[threadIdx.x+st]; rs2[threadIdx.x]+=rs2[threadIdx.x+st]; }
    __syncthreads();
  }
  if(threadIdx.x==0){
    double mu=rs[0]/32768.0;
    double var=rs2[0]/32768.0 - mu*mu;
    stats[blockIdx.x]=(float)mu;
    stats[128+blockIdx.x]=(float)(1.0/sqrt(var+1e-5));
  }
}

// ---------------- K3: groupnorm-apply + 1x1 conv + residual LFQ ----------------
// grid 512 (= b*16 + rowgrp), block 256 (1 token/thread, 4 rows x 64 cols)
__global__ __launch_bounds__(256) void k_lfq(const float* __restrict__ h2,
    const float* __restrict__ stats, const float* __restrict__ w3, const float* __restrict__ b3,
    float* __restrict__ qout, float* __restrict__ idxout,
    float* __restrict__ avgp, float* __restrict__ ec)
{
  __shared__ float tab[256*33];   // per-token lo[16]|hi[16], stride 33 (bank spread)
  __shared__ float w3s[256];
  __shared__ float b3s[8];
  const int blk=blockIdx.x;
  const int b=blk>>4;
  const int t=threadIdx.x;
  const int h=(blk&15)*4 + (t>>6);
  const int w=t&63;
  w3s[t]=w3[t];
  if(t<8) b3s[t]=b3[t];
  __syncthreads();
  float mu[4], rs[4];
  #pragma unroll
  for(int g=0;g<4;g++){ mu[g]=stats[b*4+g]; rs[g]=stats[128+b*4+g]; }
  const float* hp = h2 + (size_t)b*131072 + h*64 + w;
  float z[8];
  #pragma unroll
  for(int d=0;d<8;d++) z[d]=b3s[d];
  #pragma unroll
  for(int c=0;c<32;c++){
    float xn=(hp[(size_t)c*4096]-mu[c>>3])*rs[c>>3];
    #pragma unroll
    for(int d=0;d<8;d++) z[d]=fmaf(xn, w3s[d*32+c], z[d]);
  }
  float r[8], qsum[8];
  #pragma unroll
  for(int d=0;d<8;d++){ r[d]=z[d]; qsum[d]=0.f; }
  float entk[2], comk[2];
  #pragma unroll
  for(int k=0;k<2;k++){
    int idx=0; float ent=0.f, com=0.f;
    float pb0[8], pb1[8];
    #pragma unroll
    for(int d=0;d<8;d++){
      float rv=r[d];
      bool pos = rv>0.f;
      float sgn = pos?1.f:-1.f;
      idx |= (pos?1:0)<<d;
      float dd=rv-sgn; com=fmaf(dd,dd,com);
      // softmax over the +-1 product codebook factorizes into 8 Bernoulli bits:
      float a=400.f*fabsf(rv);
      float e=expf(-a);
      float inv=1.f/(1.f+e);
      ent += log1pf(e) + a*e*inv;     // per-bit entropy, exact closed form
      float pm=inv, pq=e*inv;         // P(bit matches sign), P(mismatch)
      pb1[d]=pos?pm:pq;
      pb0[d]=pos?pq:pm;
      qsum[d]+=sgn;
      r[d]=rv-sgn;
    }
    // split product tables: lo over bits 0..3, hi over bits 4..7 (all static idx)
    float lo[16], hi[16];
    lo[0]=pb0[0]; lo[1]=pb1[0];
    lo[2]=lo[0]*pb1[1]; lo[3]=lo[1]*pb1[1]; lo[0]*=pb0[1]; lo[1]*=pb0[1];
    lo[4]=lo[0]*pb1[2]; lo[5]=lo[1]*pb1[2]; lo[6]=lo[2]*pb1[2]; lo[7]=lo[3]*pb1[2];
    lo[0]*=pb0[2]; lo[1]*=pb0[2]; lo[2]*=pb0[2]; lo[3]*=pb0[2];
    lo[8]=lo[0]*pb1[3]; lo[9]=lo[1]*pb1[3]; lo[10]=lo[2]*pb1[3]; lo[11]=lo[3]*pb1[3];
    lo[12]=lo[4]*pb1[3]; lo[13]=lo[5]*pb1[3]; lo[14]=lo[6]*pb1[3]; lo[15]=lo[7]*pb1[3];
    lo[0]*=pb0[3]; lo[1]*=pb0[3]; lo[2]*=pb0[3]; lo[3]*=pb0[3];
    lo[4]*=pb0[3]; lo[5]*=pb0[3]; lo[6]*=pb0[3]; lo[7]*=pb0[3];
    hi[0]=pb0[4]; hi[1]=pb1[4];
    hi[2]=hi[0]*pb1[5]; hi[3]=hi[1]*pb1[5]; hi[0]*=pb0[5]; hi[1]*=pb0[5];
    hi[4]=hi[0]*pb1[6]; hi[5]=hi[1]*pb1[6]; hi[6]=hi[2]*pb1[6]; hi[7]=hi[3]*pb1[6];
    hi[0]*=pb0[6]; hi[1]*=pb0[6]; hi[2]*=pb0[6]; hi[3]*=pb0[6];
    hi[8]=hi[0]*pb1[7]; hi[9]=hi[1]*pb1[7]; hi[10]=hi[2]*pb1[7]; hi[11]=hi[3]*pb1[7];
    hi[12]=hi[4]*pb1[7]; hi[13]=hi[5]*pb1[7]; hi[14]=hi[6]*pb1[7]; hi[15]=hi[7]*pb1[7];
    hi[0]*=pb0[7]; hi[1]*=pb0[7]; hi[2]*=pb0[7]; hi[3]*=pb0[7];
    hi[4]*=pb0[7]; hi[5]*=pb0[7]; hi[6]*=pb0[7]; hi[7]*=pb0[7];
    #pragma unroll
    for(int m=0;m<16;m++){ tab[t*33+m]=lo[m]; tab[t*33+16+m]=hi[m]; }
    __syncthreads();
    // phase 2: code-parallel avg_prob partial (thread t owns code t)
    float accp=0.f;
    const int jl=t&15, jh=t>>4;
    for(int tt=0;tt<256;tt++)
      accp=fmaf(tab[tt*33+jl], tab[tt*33+16+jh], accp);
    avgp[((size_t)k*512+blk)*256+t]=accp;
    __syncthreads();
    entk[k]=ent; comk[k]=com;
    idxout[((size_t)(b*64+h)*64+w)*2+k]=(float)idx;
  }
  #pragma unroll
  for(int d=0;d<8;d++)
    qout[(((size_t)b*8+d)*64+h)*64+w]=qsum[d];
  // block-reduce entropy/commit partials (reuse tab)
  tab[t]=entk[0]; tab[256+t]=entk[1]; tab[512+t]=comk[0]; tab[768+t]=comk[1];
  __syncthreads();
  for(int st=128;st>0;st>>=1){
    if(t<st){ tab[t]+=tab[t+st]; tab[256+t]+=tab[256+t+st];
              tab[512+t]+=tab[512+t+st]; tab[768+t]+=tab[768+t+st]; }
    __syncthreads();
  }
  if(t==0){ ec[blk*4+0]=tab[0]; ec[blk*4+1]=tab[256]; ec[blk*4+2]=tab[512]; ec[blk*4+3]=tab[768]; }
}

// ---------------- K3b: final aux reduction (1 block, deterministic, f64) ----------------
__global__ __launch_bounds__(256) void k_final(const float* __restrict__ avgp,
    const float* __restrict__ ec, float* __restrict__ auxout)
{
  __shared__ double red[256];
  const int t=threadIdx.x;
  double cb=0.0;
  #pragma unroll
  for(int k=0;k<2;k++){
    double s=0.0;
    for(int blk=0;blk<512;blk++) s += (double)avgp[((size_t)k*512+blk)*256+t];
    double ap = s*(1.0/131072.0);
    cb += -(ap*log(ap+1e-10));
  }
  red[t]=cb; __syncthreads();
  for(int st=128;st>0;st>>=1){ if(t<st) red[t]+=red[t+st]; __syncthreads(); }
  double CB=red[0]; __syncthreads();
  double e=0.0,c=0.0;
  for(int blk=t;blk<512;blk+=256){
    e += (double)ec[blk*4+0]+(double)ec[blk*4+1];
    c += (double)ec[blk*4+2]+(double)ec[blk*4+3];
  }
  red[t]=e; __syncthreads();
  for(int st=128;st>0;st>>=1){ if(t<st) red[t]+=red[t+st]; __syncthreads(); }
  double E=red[0]; __syncthreads();
  red[t]=c; __syncthreads();
  for(int st=128;st>0;st>>=1){ if(t<st) red[t]+=red[t+st]; __syncthreads(); }
  if(t==0){
    double C=red[0];
    double aux = 0.1*(E*(1.0/131072.0) - CB) + C*(1.0/1048576.0);
    auxout[0]=(float)aux;
  }
}

// ---------------- K4: decoder conv d1 (8->32, 3x3, pad1) on 64x64 ----------------
// grid (4,4,32) block 256
__global__ __launch_bounds__(256) void k_dec1(const float* __restrict__ q,
    const float* __restrict__ d1, const float* __restrict__ db1, float* __restrict__ out1)
{
  __shared__ float tile[8*342];   // [ic][18][19]
  __shared__ float wsm[2304];
  __shared__ float bsm[32];
  const int b=blockIdx.z, r0=blockIdx.y*16, c0=blockIdx.x*16;
  const float* qp = q + (size_t)b*8*4096;
  for(int i=threadIdx.x;i<8*324;i+=256){
    int ic=i/324, rem=i-ic*324, r=rem/18, c=rem-r*18;
    int gr=r0+r-1, gc=c0+c-1;
    float v=0.f;
    if(gr>=0&&gr<64&&gc>=0&&gc<64) v=qp[ic*4096+gr*64+gc];
    tile[ic*342+r*19+c]=v;
  }
  for(int i=threadIdx.x;i<2304;i+=256) wsm[i]=d1[i];
  if(threadIdx.x<32) bsm[threadIdx.x]=db1[threadIdx.x];
  __syncthreads();
  const int tx=threadIdx.x&15, ty=threadIdx.x>>4;
  float acc[32];
  #pragma unroll
  for(int o=0;o<32;o++) acc[o]=bsm[o];
  #pragma unroll 2
  for(int ic=0;ic<8;ic++){
    float v[9];
    #pragma unroll
    for(int ky=0;ky<3;ky++)
      #pragma unroll
      for(int kx=0;kx<3;kx++)
        v[ky*3+kx]=tile[ic*342+(ty+ky)*19+tx+kx];
    #pragma unroll
    for(int o=0;o<32;o++){
      const float* wp=&wsm[(o*8+ic)*9];
      float s=acc[o];
      #pragma unroll
      for(int kk=0;kk<9;kk++) s=fmaf(v[kk],wp[kk],s);
      acc[o]=s;
    }
  }
  float* op = out1 + (size_t)b*32*4096 + (r0+ty)*64 + (c0+tx);
  #pragma unroll
  for(int o=0;o<32;o++) op[(size_t)o*4096]=acc[o];
}

// ---------------- K5: upsample2 + conv d2 (32->16,3x3,pad1) + gelu, at 128-res ----------------
// parity-combined 2x2 weights; 32x32 output tile, 4 px/thread (same parity),
// grid (4,4,32) block 256.  REWORK: round-0 version fully unrolled ic=32 and
// spilled (VGPR=256, 3.2GB scratch writes). 4 px/thread amortizes each float4
// weight read over 16 FMAs; #pragma unroll 2 keeps the scheduling region small.
__global__ __launch_bounds__(256) void k_dec2(const float* __restrict__ out1,
    const float* __restrict__ d2, const float* __restrict__ db2, float* __restrict__ out2)
{
  __shared__ float tile[32*342];   // [ic][18][19] src at 64-res (43.8 KB)
  __shared__ float4 wp4[2048];     // [(ic*16+oc)*4+par] (32 KB)
  __shared__ float bsm[16];
  const int b=blockIdx.z, y0=blockIdx.y*32, x0=blockIdx.x*32;
  const int sy0=(y0>>1)-1, sx0=(x0>>1)-1;
  const float* sp = out1 + (size_t)b*32*4096;
  for(int i=threadIdx.x;i<32*324;i+=256){
    int ic=i/324, rem=i-ic*324, r=rem/18, c=rem-r*18;
    int gr=sy0+r, gc=sx0+c;
    float v=0.f;
    if(gr>=0&&gr<64&&gc>=0&&gc<64) v=sp[ic*4096+gr*64+gc];
    tile[ic*342+r*19+c]=v;
  }
  for(int i=threadIdx.x;i<2048;i+=256){
    int par=i&3, oc=(i>>2)&15, ic=i>>6;
    int py=par>>1, px=par&1;
    const float* wg = d2 + ((size_t)oc*32+ic)*9;
    float a00=0.f,a01=0.f,a10=0.f,a11=0.f;
    #pragma unroll
    for(int ky=0;ky<3;ky++){
      int sy = py ? (ky>>1) : ((ky>0)?1:0);
      #pragma unroll
      for(int kx=0;kx<3;kx++){
        int sx = px ? (kx>>1) : ((kx>0)?1:0);
        float wv=wg[ky*3+kx];
        if(sy==0){ if(sx==0)a00+=wv; else a01+=wv; }
        else     { if(sx==0)a10+=wv; else a11+=wv; }
      }
    }
    wp4[i]=make_float4(a00,a01,a10,a11);
  }
  if(threadIdx.x<16) bsm[threadIdx.x]=db2[threadIdx.x];
  __syncthreads();
  const int tx=threadIdx.x&15, ty=threadIdx.x>>4;
  const int par=((ty&1)<<1)|(tx&1);
  const int byl=((ty-1)>>1)+1, bxl=((tx-1)>>1)+1;
  // 4 pixels: (ty+16a, tx+16c) -> src base (byl+8a, bxl+8c); same parity.
  float acc[16][4];
  #pragma unroll
  for(int o=0;o<16;o++){
    float bv=bsm[o];
    #pragma unroll
    for(int p=0;p<4;p++) acc[o][p]=bv;
  }
  #pragma unroll 2
  for(int ic=0;ic<32;ic++){
    const float* tp=&tile[ic*342];
    float s0[4],s1[4],s2[4],s3[4];
    #pragma unroll
    for(int a=0;a<2;a++)
      #pragma unroll
      for(int c=0;c<2;c++){
        const float* q=tp+(byl+8*a)*19+(bxl+8*c);
        int p=a*2+c;
        s0[p]=q[0]; s1[p]=q[1]; s2[p]=q[19]; s3[p]=q[20];
      }
    #pragma unroll
    for(int o=0;o<16;o++){
      float4 wv=wp4[(ic*16+o)*4+par];
      #pragma unroll
      for(int p=0;p<4;p++)
        acc[o][p]=fmaf(s0[p],wv.x,fmaf(s1[p],wv.y,fmaf(s2[p],wv.z,fmaf(s3[p],wv.w,acc[o][p]))));
    }
  }
  #pragma unroll
  for(int o=0;o<16;o++){
    float* op = out2 + ((size_t)b*16+o)*16384;
    #pragma unroll
    for(int a=0;a<2;a++)
      #pragma unroll
      for(int c=0;c<2;c++)
        op[(size_t)(y0+ty+16*a)*128 + (x0+tx+16*c)] = gelu_exact(acc[o][a*2+c]);
  }
}

// ---------------- K6: upsample2 + conv d3 (16->1,3x3,pad1) + clip, at 256-res ----------------
// grid (8,8,32) block 256, 4 px/thread (32x32 tile)
__global__ __launch_bounds__(256) void k_dec3(const float* __restrict__ out2,
    const float* __restrict__ d3, const float* __restrict__ db3, float* __restrict__ y)
{
  __shared__ float tile[16*342];   // [ic][18][19] src at 128-res
  __shared__ float4 wp4[64];       // [ic*4+par]
  const int b=blockIdx.z, y0=blockIdx.y*32, x0=blockIdx.x*32;
  const int sy0=(y0>>1)-1, sx0=(x0>>1)-1;
  const float* sp = out2 + (size_t)b*16*16384;
  for(int i=threadIdx.x;i<16*324;i+=256){
    int ic=i/324, rem=i-ic*324, r=rem/18, c=rem-r*18;
    int gr=sy0+r, gc=sx0+c;
    float v=0.f;
    if(gr>=0&&gr<128&&gc>=0&&gc<128) v=sp[ic*16384+gr*128+gc];
    tile[ic*342+r*19+c]=v;
  }
  if(threadIdx.x<64){
    int ic=threadIdx.x>>2, par=threadIdx.x&3;
    int py=par>>1, px=par&1;
    const float* wg = d3 + ic*9;
    float a00=0.f,a01=0.f,a10=0.f,a11=0.f;
    #pragma unroll
    for(int ky=0;ky<3;ky++){
      int sy = py ? (ky>>1) : ((ky>0)?1:0);
      #pragma unroll
      for(int kx=0;kx<3;kx++){
        int sx = px ? (kx>>1) : ((kx>0)?1:0);
        float wv=wg[ky*3+kx];
        if(sy==0){ if(sx==0)a00+=wv; else a01+=wv; }
        else     { if(sx==0)a10+=wv; else a11+=wv; }
      }
    }
    wp4[threadIdx.x]=make_float4(a00,a01,a10,a11);
  }
  __syncthreads();
  const float bias=db3[0];
  #pragma unroll
  for(int pi=0;pi<4;pi++){
    int p=threadIdx.x+256*pi;
    int yy=p>>5, xx=p&31;
    int par=((yy&1)<<1)|(xx&1);
    int byl=((yy-1)>>1)+1, bxl=((xx-1)>>1)+1;
    float acc=bias;
    #pragma unroll
    for(int ic=0;ic<16;ic++){
      const float* tp=&tile[ic*342+byl*19+bxl];
      float4 wv=wp4[ic*4+par];
      acc=fmaf(tp[0],wv.x,fmaf(tp[1],wv.y,fmaf(tp[19],wv.z,fmaf(tp[20],wv.w,acc))));
    }
    acc=fminf(fmaxf(acc,-1.0f),1.0f);
    y[(size_t)b*65536 + (size_t)(y0+yy)*256 + (x0+xx)] = acc;
  }
}

extern "C" void kernel_launch(void* const* d_in, const int* in_sizes, int n_in,
                              void* d_out, int out_size, void* d_ws, size_t ws_size,
                              hipStream_t stream)
{
  const float* x  =(const float*)d_in[0];
  const float* w1 =(const float*)d_in[1];
  const float* b1 =(const float*)d_in[2];
  const float* w2 =(const float*)d_in[3];
  const float* b2 =(const float*)d_in[4];
  const float* w3 =(const float*)d_in[5];
  const float* b3 =(const float*)d_in[6];
  const float* d1 =(const float*)d_in[7];
  const float* db1=(const float*)d_in[8];
  const float* d2 =(const float*)d_in[9];
  const float* db2=(const float*)d_in[10];
  const float* d3 =(const float*)d_in[11];
  const float* db3=(const float*)d_in[12];
  float* out=(float*)d_out;
  float* ws =(float*)d_ws;
  // ws layout (floats): h1[8388608] h2[4194304] q[1048576] stats[256] avgp[262144] ec[2048]
  float* h1   = ws;
  float* h2   = ws + 8388608;
  float* qb   = ws + 12582912;
  float* st   = ws + 13631488;
  float* avgp = ws + 13631744;
  float* ec   = ws + 13893888;
  float* out1 = h2;   // reuse: h2pre dead after k_lfq
  float* out2 = h1;   // reuse: h1 dead after k_conv2

  k_conv1<<<dim3(8,8,32),256,0,stream>>>(x,w1,b1,h1);
  k_conv2<<<dim3(8,8,32),512,0,stream>>>(h1,w2,b2,h2);
  k_stats<<<dim3(128),256,0,stream>>>(h2,st);
  k_lfq  <<<dim3(512),256,0,stream>>>(h2,st,w3,b3,qb,out+2097152,avgp,ec);
  k_final<<<dim3(1),256,0,stream>>>(avgp,ec,out+2359296);
  k_dec1 <<<dim3(4,4,32),256,0,stream>>>(qb,d1,db1,out1);
  k_dec2 <<<dim3(4,4,32),256,0,stream>>>(out1,d2,db2,out2);
  k_dec3 <<<dim3(8,8,32),256,0,stream>>>(out2,d3,db3,out);
}

// Round 3
// 295.089 us; speedup vs baseline: 8.8491x; 1.1196x over previous
//
#include <hip/hip_runtime.h>
#include <hip/hip_bf16.h>
#include <math.h>

#define DEV __device__ __forceinline__

DEV float gelu_exact(float x){ return 0.5f*x*(1.0f + erff(x*0.70710678118654752f)); }

// ---------------- K0: prep — weight transpose / parity-combine tables ----------------
// w2t[(ic*32+oc)*9+k] ; wp4d2[((par*32+ic)*16+oc)*4+j] ; (d3 combined in-kernel)
__global__ __launch_bounds__(512) void k_prep(const float* __restrict__ w2,
    const float* __restrict__ d2, float* __restrict__ w2t, float* __restrict__ wp4d2)
{
  const int t=threadIdx.x;
  for(int i=t;i<4608;i+=512){
    int oc=i/144, rem=i-oc*144, ic=rem/9, k=rem-ic*9;
    w2t[(ic*32+oc)*9+k]=w2[i];
  }
  for(int i=t;i<2048;i+=512){
    int par=i>>9, ic=(i>>4)&31, oc=i&15;
    int py=par>>1, px=par&1;
    const float* wg = d2 + ((size_t)oc*32+ic)*9;
    float a00=0.f,a01=0.f,a10=0.f,a11=0.f;
    #pragma unroll
    for(int ky=0;ky<3;ky++){
      int sy = py ? (ky>>1) : ((ky>0)?1:0);
      #pragma unroll
      for(int kx=0;kx<3;kx++){
        int sx = px ? (kx>>1) : ((kx>0)?1:0);
        float wv=wg[ky*3+kx];
        if(sy==0){ if(sx==0)a00+=wv; else a01+=wv; }
        else     { if(sx==0)a10+=wv; else a11+=wv; }
      }
    }
    float* dst=wp4d2+(size_t)i*4;
    dst[0]=a00; dst[1]=a01; dst[2]=a10; dst[3]=a11;
  }
}

// ---------------- K1: conv1(1->16,3x3,pad1) + maxpool2 + gelu ----------------
// grid (8,8,32) block 256; out h1 (32,16,128,128). Parity-split tile, scalar weights.
__global__ __launch_bounds__(256) void k_conv1(const float* __restrict__ x,
    const float* __restrict__ w1, const float* __restrict__ b1,
    float* __restrict__ h1)
{
  __shared__ float sE[34*19], sO[34*19];
  const int b = blockIdx.z;
  const int r0 = blockIdx.y*32, c0 = blockIdx.x*32;   // unpooled origin (256-res)
  const float* xp = x + (size_t)b*65536;
  for(int i=threadIdx.x;i<34*34;i+=256){
    int r=i/34, c=i-r*34;
    int gr=r0+r-1, gc=c0+c-1;
    float v=0.f;
    if(gr>=0 && gr<256 && gc>=0 && gc<256) v = xp[gr*256+gc];
    if(c&1) sO[r*19+(c>>1)]=v; else sE[r*19+(c>>1)]=v;
  }
  __syncthreads();
  const int tx=threadIdx.x&15, ty=threadIdx.x>>4;
  const int base = 2*ty*19 + tx;
  float in[4][4];
  #pragma unroll
  for(int r=0;r<4;r++){
    in[r][0]=sE[base+r*19]; in[r][1]=sO[base+r*19];
    in[r][2]=sE[base+r*19+1]; in[r][3]=sO[base+r*19+1];
  }
  const int py = blockIdx.y*16+ty, px = blockIdx.x*16+tx;
  float* op = h1 + ((size_t)b*16)*16384 + py*128 + px;
  #pragma unroll
  for(int ch=0;ch<16;ch++){
    float m=-1e30f;
    #pragma unroll
    for(int pr=0;pr<2;pr++)
      #pragma unroll
      for(int pc=0;pc<2;pc++){
        float a=0.f;
        #pragma unroll
        for(int ky=0;ky<3;ky++)
          #pragma unroll
          for(int kx=0;kx<3;kx++)
            a = fmaf(in[pr+ky][pc+kx], w1[ch*9+ky*3+kx], a);
        m = fmaxf(m,a);
      }
    op[(size_t)ch*16384] = gelu_exact(m + b1[ch]);
  }
}

// ---------------- K2: conv2(16->32,3x3,pad1) + maxpool2 ----------------
// grid (8,8,32) block 512; parity-split pixel LDS + scalar (transposed) weights.
__global__ __launch_bounds__(512) void k_conv2(const float* __restrict__ h1,
    const float* __restrict__ w2t, const float* __restrict__ b2,
    float* __restrict__ h2)
{
  __shared__ float sE[2880], sO[2880];   // [ic][18 rows][10 even/odd cols]
  const int b=blockIdx.z;
  const int r0=blockIdx.y*16, c0=blockIdx.x*16;  // unpooled origin (128-res)
  const float* hp = h1 + (size_t)b*16*16384;
  for(int i=threadIdx.x;i<5184;i+=512){
    int ic=i/324, rem=i-ic*324, lr=rem/18, lc=rem-lr*18;
    int gr=r0+lr-1, gc=c0+lc-1;
    float v=0.f;
    if(gr>=0&&gr<128&&gc>=0&&gc<128) v=hp[(size_t)ic*16384+gr*128+gc];
    if(lc&1) sO[ic*180+lr*10+(lc>>1)]=v; else sE[ic*180+lr*10+(lc>>1)]=v;
  }
  __syncthreads();
  const int pos=threadIdx.x&63;
  const int oc0=__builtin_amdgcn_readfirstlane((int)(threadIdx.x>>6))*4;
  const int pyl=pos>>3, pxl=pos&7;
  float acc[4][4];
  #pragma unroll
  for(int i=0;i<4;i++)
    #pragma unroll
    for(int j=0;j<4;j++) acc[i][j]=0.f;
  #pragma unroll 2
  for(int ic=0;ic<16;ic++){
    const int base = ic*180 + 2*pyl*10 + pxl;
    float in[4][4];
    #pragma unroll
    for(int r=0;r<4;r++){
      in[r][0]=sE[base+r*10]; in[r][1]=sO[base+r*10];
      in[r][2]=sE[base+r*10+1]; in[r][3]=sO[base+r*10+1];
    }
    const float* wp = w2t + (ic*32+oc0)*9;
    #pragma unroll
    for(int o=0;o<4;o++){
      #pragma unroll
      for(int pr=0;pr<2;pr++)
        #pragma unroll
        for(int pc=0;pc<2;pc++){
          float s=acc[o][pr*2+pc];
          #pragma unroll
          for(int ky=0;ky<3;ky++)
            #pragma unroll
            for(int kx=0;kx<3;kx++)
              s=fmaf(in[pr+ky][pc+kx], wp[o*9+ky*3+kx], s);
          acc[o][pr*2+pc]=s;
        }
    }
  }
  const int py=blockIdx.y*8+pyl, px=blockIdx.x*8+pxl;
  #pragma unroll
  for(int o=0;o<4;o++){
    const int oc=oc0+o;
    float m=fmaxf(fmaxf(acc[o][0],acc[o][1]),fmaxf(acc[o][2],acc[o][3]));
    h2[(((size_t)b*32+oc)*64+py)*64+px]=m+b2[oc];
  }
}

// ---------------- K2b: groupnorm stats (deterministic, f64) ----------------
__global__ __launch_bounds__(256) void k_stats(const float* __restrict__ h2,
                                               float* __restrict__ stats)
{
  const int b=blockIdx.x>>2, g=blockIdx.x&3;
  const float* p = h2 + ((size_t)b*32 + g*8)*4096;
  double s=0.0, s2=0.0;
  for(int i=threadIdx.x;i<32768;i+=256){ float v=p[i]; s+=v; s2+=(double)v*v; }
  __shared__ double rs[256], rs2[256];
  rs[threadIdx.x]=s; rs2[threadIdx.x]=s2; __syncthreads();
  for(int st=128;st>0;st>>=1){
    if(threadIdx.x<st){ rs[threadIdx.x]+=rs[threadIdx.x+st]; rs2[threadIdx.x]+=rs2[threadIdx.x+st]; }
    __syncthreads();
  }
  if(threadIdx.x==0){
    double mu=rs[0]/32768.0;
    double var=rs2[0]/32768.0 - mu*mu;
    stats[blockIdx.x]=(float)mu;
    stats[128+blockIdx.x]=(float)(1.0/sqrt(var+1e-5));
  }
}

// ---------------- K3: groupnorm-apply + 1x1 conv + residual LFQ ----------------
__global__ __launch_bounds__(256) void k_lfq(const float* __restrict__ h2,
    const float* __restrict__ stats, const float* __restrict__ w3, const float* __restrict__ b3,
    float* __restrict__ qout, float* __restrict__ idxout,
    float* __restrict__ avgp, float* __restrict__ ec)
{
  __shared__ float tab[256*33];   // per-token lo[16]|hi[16], stride 33 (bank spread)
  const int blk=blockIdx.x;
  const int b=blk>>4;
  const int t=threadIdx.x;
  const int h=(blk&15)*4 + (t>>6);
  const int w=t&63;
  float mu[4], rs[4];
  #pragma unroll
  for(int g=0;g<4;g++){ mu[g]=stats[b*4+g]; rs[g]=stats[128+b*4+g]; }
  const float* hp = h2 + (size_t)b*131072 + h*64 + w;
  float z[8];
  #pragma unroll
  for(int d=0;d<8;d++) z[d]=b3[d];
  #pragma unroll
  for(int c=0;c<32;c++){
    float xn=(hp[(size_t)c*4096]-mu[c>>3])*rs[c>>3];
    #pragma unroll
    for(int d=0;d<8;d++) z[d]=fmaf(xn, w3[d*32+c], z[d]);
  }
  float r[8], qsum[8];
  #pragma unroll
  for(int d=0;d<8;d++){ r[d]=z[d]; qsum[d]=0.f; }
  float entk[2], comk[2];
  #pragma unroll
  for(int k=0;k<2;k++){
    int idx=0; float ent=0.f, com=0.f;
    float pb0[8], pb1[8];
    #pragma unroll
    for(int d=0;d<8;d++){
      float rv=r[d];
      bool pos = rv>0.f;
      float sgn = pos?1.f:-1.f;
      idx |= (pos?1:0)<<d;
      float dd=rv-sgn; com=fmaf(dd,dd,com);
      float a=400.f*fabsf(rv);
      float e=expf(-a);
      float inv=1.f/(1.f+e);
      ent += log1pf(e) + a*e*inv;     // per-bit entropy, exact closed form
      float pm=inv, pq=e*inv;
      pb1[d]=pos?pm:pq;
      pb0[d]=pos?pq:pm;
      qsum[d]+=sgn;
      r[d]=rv-sgn;
    }
    float lo[16], hi[16];
    lo[0]=pb0[0]; lo[1]=pb1[0];
    lo[2]=lo[0]*pb1[1]; lo[3]=lo[1]*pb1[1]; lo[0]*=pb0[1]; lo[1]*=pb0[1];
    lo[4]=lo[0]*pb1[2]; lo[5]=lo[1]*pb1[2]; lo[6]=lo[2]*pb1[2]; lo[7]=lo[3]*pb1[2];
    lo[0]*=pb0[2]; lo[1]*=pb0[2]; lo[2]*=pb0[2]; lo[3]*=pb0[2];
    lo[8]=lo[0]*pb1[3]; lo[9]=lo[1]*pb1[3]; lo[10]=lo[2]*pb1[3]; lo[11]=lo[3]*pb1[3];
    lo[12]=lo[4]*pb1[3]; lo[13]=lo[5]*pb1[3]; lo[14]=lo[6]*pb1[3]; lo[15]=lo[7]*pb1[3];
    lo[0]*=pb0[3]; lo[1]*=pb0[3]; lo[2]*=pb0[3]; lo[3]*=pb0[3];
    lo[4]*=pb0[3]; lo[5]*=pb0[3]; lo[6]*=pb0[3]; lo[7]*=pb0[3];
    hi[0]=pb0[4]; hi[1]=pb1[4];
    hi[2]=hi[0]*pb1[5]; hi[3]=hi[1]*pb1[5]; hi[0]*=pb0[5]; hi[1]*=pb0[5];
    hi[4]=hi[0]*pb1[6]; hi[5]=hi[1]*pb1[6]; hi[6]=hi[2]*pb1[6]; hi[7]=hi[3]*pb1[6];
    hi[0]*=pb0[6]; hi[1]*=pb0[6]; hi[2]*=pb0[6]; hi[3]*=pb0[6];
    hi[8]=hi[0]*pb1[7]; hi[9]=hi[1]*pb1[7]; hi[10]=hi[2]*pb1[7]; hi[11]=hi[3]*pb1[7];
    hi[12]=hi[4]*pb1[7]; hi[13]=hi[5]*pb1[7]; hi[14]=hi[6]*pb1[7]; hi[15]=hi[7]*pb1[7];
    hi[0]*=pb0[7]; hi[1]*=pb0[7]; hi[2]*=pb0[7]; hi[3]*=pb0[7];
    hi[4]*=pb0[7]; hi[5]*=pb0[7]; hi[6]*=pb0[7]; hi[7]*=pb0[7];
    #pragma unroll
    for(int m=0;m<16;m++){ tab[t*33+m]=lo[m]; tab[t*33+16+m]=hi[m]; }
    __syncthreads();
    float accp=0.f;
    const int jl=t&15, jh=t>>4;
    for(int tt=0;tt<256;tt++)
      accp=fmaf(tab[tt*33+jl], tab[tt*33+16+jh], accp);
    avgp[((size_t)k*512+blk)*256+t]=accp;
    __syncthreads();
    entk[k]=ent; comk[k]=com;
    idxout[((size_t)(b*64+h)*64+w)*2+k]=(float)idx;
  }
  #pragma unroll
  for(int d=0;d<8;d++)
    qout[(((size_t)b*8+d)*64+h)*64+w]=qsum[d];
  tab[t]=entk[0]; tab[256+t]=entk[1]; tab[512+t]=comk[0]; tab[768+t]=comk[1];
  __syncthreads();
  for(int st=128;st>0;st>>=1){
    if(t<st){ tab[t]+=tab[t+st]; tab[256+t]+=tab[256+t+st];
              tab[512+t]+=tab[512+t+st]; tab[768+t]+=tab[768+t+st]; }
    __syncthreads();
  }
  if(t==0){ ec[blk*4+0]=tab[0]; ec[blk*4+1]=tab[256]; ec[blk*4+2]=tab[512]; ec[blk*4+3]=tab[768]; }
}

// ---------------- K3b: final aux reduction (1 block, deterministic, f64) ----------------
__global__ __launch_bounds__(256) void k_final(const float* __restrict__ avgp,
    const float* __restrict__ ec, float* __restrict__ auxout)
{
  __shared__ double red[256];
  const int t=threadIdx.x;
  double cb=0.0;
  #pragma unroll
  for(int k=0;k<2;k++){
    double s=0.0;
    for(int blk=0;blk<512;blk++) s += (double)avgp[((size_t)k*512+blk)*256+t];
    double ap = s*(1.0/131072.0);
    cb += -(ap*log(ap+1e-10));
  }
  red[t]=cb; __syncthreads();
  for(int st=128;st>0;st>>=1){ if(t<st) red[t]+=red[t+st]; __syncthreads(); }
  double CB=red[0]; __syncthreads();
  double e=0.0,c=0.0;
  for(int blk=t;blk<512;blk+=256){
    e += (double)ec[blk*4+0]+(double)ec[blk*4+1];
    c += (double)ec[blk*4+2]+(double)ec[blk*4+3];
  }
  red[t]=e; __syncthreads();
  for(int st=128;st>0;st>>=1){ if(t<st) red[t]+=red[t+st]; __syncthreads(); }
  double E=red[0]; __syncthreads();
  red[t]=c; __syncthreads();
  for(int st=128;st>0;st>>=1){ if(t<st) red[t]+=red[t+st]; __syncthreads(); }
  if(t==0){
    double C=red[0];
    double aux = 0.1*(E*(1.0/131072.0) - CB) + C*(1.0/1048576.0);
    auxout[0]=(float)aux;
  }
}

// ---------------- K4: decoder conv d1 (8->32, 3x3, pad1) on 64x64 ----------------
// grid (4,4,32) block 256; weights via scalar loads (uniform idx)
__global__ __launch_bounds__(256) void k_dec1(const float* __restrict__ q,
    const float* __restrict__ d1, const float* __restrict__ db1, float* __restrict__ out1)
{
  __shared__ float tile[8*342];   // [ic][18][19]
  const int b=blockIdx.z, r0=blockIdx.y*16, c0=blockIdx.x*16;
  const float* qp = q + (size_t)b*8*4096;
  for(int i=threadIdx.x;i<8*324;i+=256){
    int ic=i/324, rem=i-ic*324, r=rem/18, c=rem-r*18;
    int gr=r0+r-1, gc=c0+c-1;
    float v=0.f;
    if(gr>=0&&gr<64&&gc>=0&&gc<64) v=qp[ic*4096+gr*64+gc];
    tile[ic*342+r*19+c]=v;
  }
  __syncthreads();
  const int tx=threadIdx.x&15, ty=threadIdx.x>>4;
  float acc[32];
  #pragma unroll
  for(int o=0;o<32;o++) acc[o]=db1[o];
  #pragma unroll 1
  for(int ic=0;ic<8;ic++){
    float v[9];
    #pragma unroll
    for(int ky=0;ky<3;ky++)
      #pragma unroll
      for(int kx=0;kx<3;kx++)
        v[ky*3+kx]=tile[ic*342+(ty+ky)*19+tx+kx];
    #pragma unroll
    for(int o=0;o<32;o++){
      const float* wp=&d1[(o*8+ic)*9];
      float s=acc[o];
      #pragma unroll
      for(int kk=0;kk<9;kk++) s=fmaf(v[kk],wp[kk],s);
      acc[o]=s;
    }
  }
  float* op = out1 + (size_t)b*32*4096 + (r0+ty)*64 + (c0+tx);
  #pragma unroll
  for(int o=0;o<32;o++) op[(size_t)o*4096]=acc[o];
}

// ---------------- K5: upsample2 + conv d2 (32->16,3x3,pad1) + gelu, at 128-res ----------------
// wave-uniform parity; weights via scalar loads from prep'd wp4d2; 4 px/lane.
// grid (4,4,32) block 256 (4 waves, one parity each)
__global__ __launch_bounds__(256) void k_dec2(const float* __restrict__ out1,
    const float* __restrict__ wp4d2, const float* __restrict__ db2, float* __restrict__ out2)
{
  __shared__ float tile[32*342];   // [ic][18][19] src at 64-res
  const int b=blockIdx.z, y0=blockIdx.y*32, x0=blockIdx.x*32;
  const int sy0=(y0>>1)-1, sx0=(x0>>1)-1;
  const float* sp = out1 + (size_t)b*32*4096;
  for(int i=threadIdx.x;i<32*324;i+=256){
    int ic=i/324, rem=i-ic*324, r=rem/18, c=rem-r*18;
    int gr=sy0+r, gc=sx0+c;
    float v=0.f;
    if(gr>=0&&gr<64&&gc>=0&&gc<64) v=sp[ic*4096+gr*64+gc];
    tile[ic*342+r*19+c]=v;
  }
  __syncthreads();
  const int par=__builtin_amdgcn_readfirstlane((int)(threadIdx.x>>6));
  const int py=par>>1, px=par&1;
  const int l=threadIdx.x&63, r0l=l>>4, cl=l&15;
  const int bxl=cl+px;
  float acc[16][4];
  #pragma unroll
  for(int o=0;o<16;o++){
    float bv=db2[o];
    #pragma unroll
    for(int a=0;a<4;a++) acc[o][a]=bv;
  }
  #pragma unroll 2
  for(int ic=0;ic<32;ic++){
    const float* wq = wp4d2 + (size_t)((par*32+ic)*16)*4;   // 64 uniform floats
    float s00[4],s01[4],s10[4],s11[4];
    #pragma unroll
    for(int a=0;a<4;a++){
      const int byl=r0l+4*a+py;
      const float* tp=&tile[ic*342 + byl*19 + bxl];
      s00[a]=tp[0]; s01[a]=tp[1]; s10[a]=tp[19]; s11[a]=tp[20];
    }
    #pragma unroll
    for(int o=0;o<16;o++){
      const float wx=wq[o*4], wy=wq[o*4+1], wz=wq[o*4+2], ww=wq[o*4+3];
      #pragma unroll
      for(int a=0;a<4;a++)
        acc[o][a]=fmaf(s00[a],wx,fmaf(s01[a],wy,fmaf(s10[a],wz,fmaf(s11[a],ww,acc[o][a]))));
    }
  }
  #pragma unroll
  for(int o=0;o<16;o++){
    float* op = out2 + ((size_t)b*16+o)*16384;
    #pragma unroll
    for(int a=0;a<4;a++){
      const int yy=2*(r0l+4*a)+py, xx=2*cl+px;
      op[(size_t)(y0+yy)*128 + (x0+xx)] = gelu_exact(acc[o][a]);
    }
  }
}

// ---------------- K6: upsample2 + conv d3 (16->1,3x3,pad1) + clip, at 256-res ----------------
// wave-uniform parity; weight table broadcast from LDS; 4 px/lane.
// grid (8,8,32) block 256
__global__ __launch_bounds__(256) void k_dec3(const float* __restrict__ out2,
    const float* __restrict__ d3, const float* __restrict__ db3, float* __restrict__ y)
{
  __shared__ float tile[16*342];   // [ic][18][19] src at 128-res
  __shared__ float4 wp4[64];       // [par*16+ic]
  const int b=blockIdx.z, y0=blockIdx.y*32, x0=blockIdx.x*32;
  const int sy0=(y0>>1)-1, sx0=(x0>>1)-1;
  const float* sp = out2 + (size_t)b*16*16384;
  for(int i=threadIdx.x;i<16*324;i+=256){
    int ic=i/324, rem=i-ic*324, r=rem/18, c=rem-r*18;
    int gr=sy0+r, gc=sx0+c;
    float v=0.f;
    if(gr>=0&&gr<128&&gc>=0&&gc<128) v=sp[ic*16384+gr*128+gc];
    tile[ic*342+r*19+c]=v;
  }
  if(threadIdx.x<64){
    int par=threadIdx.x>>4, ic=threadIdx.x&15;
    int py=par>>1, px=par&1;
    const float* wg = d3 + ic*9;
    float a00=0.f,a01=0.f,a10=0.f,a11=0.f;
    #pragma unroll
    for(int ky=0;ky<3;ky++){
      int sy = py ? (ky>>1) : ((ky>0)?1:0);
      #pragma unroll
      for(int kx=0;kx<3;kx++){
        int sx = px ? (kx>>1) : ((kx>0)?1:0);
        float wv=wg[ky*3+kx];
        if(sy==0){ if(sx==0)a00+=wv; else a01+=wv; }
        else     { if(sx==0)a10+=wv; else a11+=wv; }
      }
    }
    wp4[threadIdx.x]=make_float4(a00,a01,a10,a11);
  }
  __syncthreads();
  const float bias=db3[0];
  const int par=__builtin_amdgcn_readfirstlane((int)(threadIdx.x>>6));
  const int py=par>>1, px=par&1;
  const int l=threadIdx.x&63, r0l=l>>4, cl=l&15;
  const int bxl=cl+px;
  float acc[4];
  #pragma unroll
  for(int a=0;a<4;a++) acc[a]=bias;
  #pragma unroll 2
  for(int ic=0;ic<16;ic++){
    const float4 wv=wp4[par*16+ic];   // wave-uniform -> broadcast
    #pragma unroll
    for(int a=0;a<4;a++){
      const int byl=r0l+4*a+py;
      const float* tp=&tile[ic*342 + byl*19 + bxl];
      acc[a]=fmaf(tp[0],wv.x,fmaf(tp[1],wv.y,fmaf(tp[19],wv.z,fmaf(tp[20],wv.w,acc[a]))));
    }
  }
  #pragma unroll
  for(int a=0;a<4;a++){
    const int yy=2*(r0l+4*a)+py, xx=2*cl+px;
    float v=fminf(fmaxf(acc[a],-1.0f),1.0f);
    y[(size_t)b*65536 + (size_t)(y0+yy)*256 + (x0+xx)] = v;
  }
}

extern "C" void kernel_launch(void* const* d_in, const int* in_sizes, int n_in,
                              void* d_out, int out_size, void* d_ws, size_t ws_size,
                              hipStream_t stream)
{
  const float* x  =(const float*)d_in[0];
  const float* w1 =(const float*)d_in[1];
  const float* b1 =(const float*)d_in[2];
  const float* w2 =(const float*)d_in[3];
  const float* b2 =(const float*)d_in[4];
  const float* w3 =(const float*)d_in[5];
  const float* b3 =(const float*)d_in[6];
  const float* d1 =(const float*)d_in[7];
  const float* db1=(const float*)d_in[8];
  const float* d2 =(const float*)d_in[9];
  const float* db2=(const float*)d_in[10];
  const float* d3 =(const float*)d_in[11];
  const float* db3=(const float*)d_in[12];
  float* out=(float*)d_out;
  float* ws =(float*)d_ws;
  // ws layout (floats):
  // h1[8388608] | h2[4194304] | qb[1048576] | st[256] | avgp[262144] | ec[2048] | wp4d2[8192]
  // w2t (4608) aliases the head of avgp: written by k_prep, consumed by k_conv2,
  // then overwritten by k_lfq's avgp (conv2 completes first in stream order).
  float* h1   = ws;
  float* h2   = ws + 8388608;
  float* qb   = ws + 12582912;
  float* st   = ws + 13631488;
  float* avgp = ws + 13631744;
  float* ec   = ws + 13893888;
  float* w2t  = avgp;
  float* wp4d2= ws + 13895936;
  float* out1 = h2;   // reuse: h2 dead after k_lfq
  float* out2 = h1;   // reuse: h1 dead after k_conv2

  k_prep <<<dim3(1),512,0,stream>>>(w2,d2,w2t,wp4d2);
  k_conv1<<<dim3(8,8,32),256,0,stream>>>(x,w1,b1,h1);
  k_conv2<<<dim3(8,8,32),512,0,stream>>>(h1,w2t,b2,h2);
  k_stats<<<dim3(128),256,0,stream>>>(h2,st);
  k_lfq  <<<dim3(512),256,0,stream>>>(h2,st,w3,b3,qb,out+2097152,avgp,ec);
  k_final<<<dim3(1),256,0,stream>>>(avgp,ec,out+2359296);
  k_dec1 <<<dim3(4,4,32),256,0,stream>>>(qb,d1,db1,out1);
  k_dec2 <<<dim3(4,4,32),256,0,stream>>>(out1,wp4d2,db2,out2);
  k_dec3 <<<dim3(8,8,32),256,0,stream>>>(out2,d3,db3,out);
}

// Round 4
// 276.910 us; speedup vs baseline: 9.4300x; 1.0656x over previous
//
#include <hip/hip_runtime.h>
#include <hip/hip_bf16.h>
#include <math.h>

#define DEV __device__ __forceinline__

DEV float gelu_exact(float x){ return 0.5f*x*(1.0f + erff(x*0.70710678118654752f)); }

// ---------------- K0: prep — weight transpose / parity-combine tables ----------------
// w2t[(ic*32+oc)*9+k] ; wp4d2[((par*32+ic)*16+oc)*4+j]
__global__ __launch_bounds__(512) void k_prep(const float* __restrict__ w2,
    const float* __restrict__ d2, float* __restrict__ w2t, float* __restrict__ wp4d2)
{
  const int t=threadIdx.x;
  for(int i=t;i<4608;i+=512){
    int oc=i/144, rem=i-oc*144, ic=rem/9, k=rem-ic*9;
    w2t[(ic*32+oc)*9+k]=w2[i];
  }
  for(int i=t;i<2048;i+=512){
    int par=i>>9, ic=(i>>4)&31, oc=i&15;
    int py=par>>1, px=par&1;
    const float* wg = d2 + ((size_t)oc*32+ic)*9;
    float a00=0.f,a01=0.f,a10=0.f,a11=0.f;
    #pragma unroll
    for(int ky=0;ky<3;ky++){
      int sy = py ? (ky>>1) : ((ky>0)?1:0);
      #pragma unroll
      for(int kx=0;kx<3;kx++){
        int sx = px ? (kx>>1) : ((kx>0)?1:0);
        float wv=wg[ky*3+kx];
        if(sy==0){ if(sx==0)a00+=wv; else a01+=wv; }
        else     { if(sx==0)a10+=wv; else a11+=wv; }
      }
    }
    float* dst=wp4d2+(size_t)i*4;
    dst[0]=a00; dst[1]=a01; dst[2]=a10; dst[3]=a11;
  }
}

// ---------------- K1: conv1(1->16,3x3,pad1) + maxpool2 + gelu ----------------
__global__ __launch_bounds__(256) void k_conv1(const float* __restrict__ x,
    const float* __restrict__ w1, const float* __restrict__ b1,
    float* __restrict__ h1)
{
  __shared__ float sE[34*19], sO[34*19];
  const int b = blockIdx.z;
  const int r0 = blockIdx.y*32, c0 = blockIdx.x*32;
  const float* xp = x + (size_t)b*65536;
  for(int i=threadIdx.x;i<34*34;i+=256){
    int r=i/34, c=i-r*34;
    int gr=r0+r-1, gc=c0+c-1;
    float v=0.f;
    if(gr>=0 && gr<256 && gc>=0 && gc<256) v = xp[gr*256+gc];
    if(c&1) sO[r*19+(c>>1)]=v; else sE[r*19+(c>>1)]=v;
  }
  __syncthreads();
  const int tx=threadIdx.x&15, ty=threadIdx.x>>4;
  const int base = 2*ty*19 + tx;
  float in[4][4];
  #pragma unroll
  for(int r=0;r<4;r++){
    in[r][0]=sE[base+r*19]; in[r][1]=sO[base+r*19];
    in[r][2]=sE[base+r*19+1]; in[r][3]=sO[base+r*19+1];
  }
  const int py = blockIdx.y*16+ty, px = blockIdx.x*16+tx;
  float* op = h1 + ((size_t)b*16)*16384 + py*128 + px;
  #pragma unroll
  for(int ch=0;ch<16;ch++){
    float m=-1e30f;
    #pragma unroll
    for(int pr=0;pr<2;pr++)
      #pragma unroll
      for(int pc=0;pc<2;pc++){
        float a=0.f;
        #pragma unroll
        for(int ky=0;ky<3;ky++)
          #pragma unroll
          for(int kx=0;kx<3;kx++)
            a = fmaf(in[pr+ky][pc+kx], w1[ch*9+ky*3+kx], a);
        m = fmaxf(m,a);
      }
    op[(size_t)ch*16384] = gelu_exact(m + b1[ch]);
  }
}

// ---------------- K2: conv2(16->32,3x3,pad1) + maxpool2 ----------------
// block 256 (4 waves x 8 oc); float2-interleaved LDS tile [ic][18][10 float2]
__global__ __launch_bounds__(256) void k_conv2(const float* __restrict__ h1,
    const float* __restrict__ w2t, const float* __restrict__ b2,
    float* __restrict__ h2)
{
  __shared__ __align__(16) float t2[16*360];   // words [ic][18][20]
  const int b=blockIdx.z;
  const int r0=blockIdx.y*16, c0=blockIdx.x*16;  // unpooled origin (128-res)
  const float* hp = h1 + (size_t)b*16*16384;
  for(int i=threadIdx.x;i<2592;i+=256){
    int ic=i/162, rem=i-ic*162, lr=rem/9, jp=rem-lr*9;
    int gr=r0+lr-1, gc=c0+2*jp-1;
    float v0=0.f, v1=0.f;
    if(gr>=0&&gr<128){
      const float* row=hp+(size_t)ic*16384+(size_t)gr*128;
      if(gc>=0&&gc<128) v0=row[gc];
      if(gc+1<128)      v1=row[gc+1];
    }
    *(float2*)&t2[ic*360+lr*20+2*jp]=make_float2(v0,v1);
  }
  __syncthreads();
  const int pos=threadIdx.x&63;
  const int oc0=__builtin_amdgcn_readfirstlane((int)(threadIdx.x>>6))*8;
  const int pyl=pos>>3, pxl=pos&7;
  const int base0 = 2*pyl*20 + 2*pxl;
  float acc[8][4];
  #pragma unroll
  for(int o=0;o<8;o++)
    #pragma unroll
    for(int j=0;j<4;j++) acc[o][j]=0.f;
  #pragma unroll 4
  for(int ic=0;ic<16;ic++){
    float in[4][4];
    #pragma unroll
    for(int r=0;r<4;r++){
      float2 a=*(const float2*)&t2[ic*360 + base0 + r*20];
      float2 c=*(const float2*)&t2[ic*360 + base0 + r*20 + 2];
      in[r][0]=a.x; in[r][1]=a.y; in[r][2]=c.x; in[r][3]=c.y;
    }
    const float* wp = w2t + (ic*32+oc0)*9;
    #pragma unroll
    for(int o=0;o<8;o++){
      #pragma unroll
      for(int pr=0;pr<2;pr++)
        #pragma unroll
        for(int pc=0;pc<2;pc++){
          float s=acc[o][pr*2+pc];
          #pragma unroll
          for(int ky=0;ky<3;ky++)
            #pragma unroll
            for(int kx=0;kx<3;kx++)
              s=fmaf(in[pr+ky][pc+kx], wp[o*9+ky*3+kx], s);
          acc[o][pr*2+pc]=s;
        }
    }
  }
  const int py=blockIdx.y*8+pyl, px=blockIdx.x*8+pxl;
  #pragma unroll
  for(int o=0;o<8;o++){
    const int oc=oc0+o;
    float m=fmaxf(fmaxf(acc[o][0],acc[o][1]),fmaxf(acc[o][2],acc[o][3]));
    h2[(((size_t)b*32+oc)*64+py)*64+px]=m+b2[oc];
  }
}

// ---------------- K2b: groupnorm stats (deterministic, f64) ----------------
__global__ __launch_bounds__(256) void k_stats(const float* __restrict__ h2,
                                               float* __restrict__ stats)
{
  const int b=blockIdx.x>>2, g=blockIdx.x&3;
  const float* p = h2 + ((size_t)b*32 + g*8)*4096;
  double s=0.0, s2=0.0;
  for(int i=threadIdx.x;i<32768;i+=256){ float v=p[i]; s+=v; s2+=(double)v*v; }
  __shared__ double rs[256], rs2[256];
  rs[threadIdx.x]=s; rs2[threadIdx.x]=s2; __syncthreads();
  for(int st=128;st>0;st>>=1){
    if(threadIdx.x<st){ rs[threadIdx.x]+=rs[threadIdx.x+st]; rs2[threadIdx.x]+=rs2[threadIdx.x+st]; }
    __syncthreads();
  }
  if(threadIdx.x==0){
    double mu=rs[0]/32768.0;
    double var=rs2[0]/32768.0 - mu*mu;
    stats[blockIdx.x]=(float)mu;
    stats[128+blockIdx.x]=(float)(1.0/sqrt(var+1e-5));
  }
}

// ---------------- K3: groupnorm-apply + 1x1 conv + residual LFQ ----------------
// Phase-2 avg_prob is a 16x16 = Lo^T(256x16) x Hi(256x16) GEMM in LDS, float4 reads.
__global__ __launch_bounds__(256) void k_lfq(const float* __restrict__ h2,
    const float* __restrict__ stats, const float* __restrict__ w3, const float* __restrict__ b3,
    float* __restrict__ qout, float* __restrict__ idxout,
    float* __restrict__ avgp, float* __restrict__ ec)
{
  __shared__ __align__(16) float tabL[16*260];  // [jl][260 tokens padded]
  __shared__ __align__(16) float tabH[16*260];  // [jh][260]
  const int blk=blockIdx.x;
  const int b=blk>>4;
  const int t=threadIdx.x;
  const int h=(blk&15)*4 + (t>>6);
  const int w=t&63;
  float mu[4], rs[4];
  #pragma unroll
  for(int g=0;g<4;g++){ mu[g]=stats[b*4+g]; rs[g]=stats[128+b*4+g]; }
  const float* hp = h2 + (size_t)b*131072 + h*64 + w;
  float z[8];
  #pragma unroll
  for(int d=0;d<8;d++) z[d]=b3[d];
  #pragma unroll
  for(int c=0;c<32;c++){
    float xn=(hp[(size_t)c*4096]-mu[c>>3])*rs[c>>3];
    #pragma unroll
    for(int d=0;d<8;d++) z[d]=fmaf(xn, w3[d*32+c], z[d]);
  }
  float r[8], qsum[8];
  #pragma unroll
  for(int d=0;d<8;d++){ r[d]=z[d]; qsum[d]=0.f; }
  float entk[2], comk[2];
  #pragma unroll
  for(int k=0;k<2;k++){
    int idx=0; float ent=0.f, com=0.f;
    float pb0[8], pb1[8];
    #pragma unroll
    for(int d=0;d<8;d++){
      float rv=r[d];
      bool pos = rv>0.f;
      float sgn = pos?1.f:-1.f;
      idx |= (pos?1:0)<<d;
      float dd=rv-sgn; com=fmaf(dd,dd,com);
      float a=400.f*fabsf(rv);
      float e=expf(-a);
      float inv=1.f/(1.f+e);
      ent += log1pf(e) + a*e*inv;     // per-bit entropy, exact closed form
      float pm=inv, pq=e*inv;
      pb1[d]=pos?pm:pq;
      pb0[d]=pos?pq:pm;
      qsum[d]+=sgn;
      r[d]=rv-sgn;
    }
    float lo[16], hi[16];
    lo[0]=pb0[0]; lo[1]=pb1[0];
    lo[2]=lo[0]*pb1[1]; lo[3]=lo[1]*pb1[1]; lo[0]*=pb0[1]; lo[1]*=pb0[1];
    lo[4]=lo[0]*pb1[2]; lo[5]=lo[1]*pb1[2]; lo[6]=lo[2]*pb1[2]; lo[7]=lo[3]*pb1[2];
    lo[0]*=pb0[2]; lo[1]*=pb0[2]; lo[2]*=pb0[2]; lo[3]*=pb0[2];
    lo[8]=lo[0]*pb1[3]; lo[9]=lo[1]*pb1[3]; lo[10]=lo[2]*pb1[3]; lo[11]=lo[3]*pb1[3];
    lo[12]=lo[4]*pb1[3]; lo[13]=lo[5]*pb1[3]; lo[14]=lo[6]*pb1[3]; lo[15]=lo[7]*pb1[3];
    lo[0]*=pb0[3]; lo[1]*=pb0[3]; lo[2]*=pb0[3]; lo[3]*=pb0[3];
    lo[4]*=pb0[3]; lo[5]*=pb0[3]; lo[6]*=pb0[3]; lo[7]*=pb0[3];
    hi[0]=pb0[4]; hi[1]=pb1[4];
    hi[2]=hi[0]*pb1[5]; hi[3]=hi[1]*pb1[5]; hi[0]*=pb0[5]; hi[1]*=pb0[5];
    hi[4]=hi[0]*pb1[6]; hi[5]=hi[1]*pb1[6]; hi[6]=hi[2]*pb1[6]; hi[7]=hi[3]*pb1[6];
    hi[0]*=pb0[6]; hi[1]*=pb0[6]; hi[2]*=pb0[6]; hi[3]*=pb0[6];
    hi[8]=hi[0]*pb1[7]; hi[9]=hi[1]*pb1[7]; hi[10]=hi[2]*pb1[7]; hi[11]=hi[3]*pb1[7];
    hi[12]=hi[4]*pb1[7]; hi[13]=hi[5]*pb1[7]; hi[14]=hi[6]*pb1[7]; hi[15]=hi[7]*pb1[7];
    hi[0]*=pb0[7]; hi[1]*=pb0[7]; hi[2]*=pb0[7]; hi[3]*=pb0[7];
    hi[4]*=pb0[7]; hi[5]*=pb0[7]; hi[6]*=pb0[7]; hi[7]*=pb0[7];
    #pragma unroll
    for(int m=0;m<16;m++){ tabL[m*260+t]=lo[m]; tabH[m*260+t]=hi[m]; }
    __syncthreads();
    // phase 2: thread t owns code (jh,jl); 64 float4 MAC steps over tokens
    float accp=0.f;
    const int jl=t&15, jh=t>>4;
    const float* Lp=&tabL[jl*260];
    const float* Hp=&tabH[jh*260];
    #pragma unroll 4
    for(int q4=0;q4<64;q4++){
      float4 L=*(const float4*)&Lp[q4*4];
      float4 H=*(const float4*)&Hp[q4*4];
      accp=fmaf(L.x,H.x,accp); accp=fmaf(L.y,H.y,accp);
      accp=fmaf(L.z,H.z,accp); accp=fmaf(L.w,H.w,accp);
    }
    avgp[((size_t)k*512+blk)*256+t]=accp;
    __syncthreads();
    entk[k]=ent; comk[k]=com;
    idxout[((size_t)(b*64+h)*64+w)*2+k]=(float)idx;
  }
  #pragma unroll
  for(int d=0;d<8;d++)
    qout[(((size_t)b*8+d)*64+h)*64+w]=qsum[d];
  tabL[t]=entk[0]; tabL[256+t]=entk[1]; tabL[512+t]=comk[0]; tabL[768+t]=comk[1];
  __syncthreads();
  for(int st=128;st>0;st>>=1){
    if(t<st){ tabL[t]+=tabL[t+st]; tabL[256+t]+=tabL[256+t+st];
              tabL[512+t]+=tabL[512+t+st]; tabL[768+t]+=tabL[768+t+st]; }
    __syncthreads();
  }
  if(t==0){ ec[blk*4+0]=tabL[0]; ec[blk*4+1]=tabL[256]; ec[blk*4+2]=tabL[512]; ec[blk*4+3]=tabL[768]; }
}

// ---------------- K3r: parallel avgp reduction (32 blocks) ----------------
// avgs[k*256+code] = sum over 512 blocks of avgp
__global__ __launch_bounds__(256) void k_red(const float* __restrict__ avgp,
    float* __restrict__ avgs)
{
  const int k=blockIdx.x>>4, c0=(blockIdx.x&15)*16;
  const int col=threadIdx.x&15, rg=threadIdx.x>>4;
  float s=0.f;
  for(int j=0;j<32;j++){
    int blk=rg+16*j;
    s+=avgp[((size_t)k*512+blk)*256+c0+col];
  }
  __shared__ float red[256];
  red[threadIdx.x]=s; __syncthreads();
  for(int st=128;st>=16;st>>=1){
    if(threadIdx.x<st) red[threadIdx.x]+=red[threadIdx.x+st];
    __syncthreads();
  }
  if(threadIdx.x<16) avgs[k*256+c0+threadIdx.x]=red[threadIdx.x];
}

// ---------------- K3b: final aux (1 block, deterministic, f64) ----------------
__global__ __launch_bounds__(256) void k_final(const float* __restrict__ avgs,
    const float* __restrict__ ec, float* __restrict__ auxout)
{
  __shared__ double red[256];
  const int t=threadIdx.x;
  double cb=0.0;
  #pragma unroll
  for(int k=0;k<2;k++){
    double ap=(double)avgs[k*256+t]*(1.0/131072.0);
    cb += -(ap*log(ap+1e-10));
  }
  red[t]=cb; __syncthreads();
  for(int st=128;st>0;st>>=1){ if(t<st) red[t]+=red[t+st]; __syncthreads(); }
  double CB=red[0]; __syncthreads();
  double e=0.0,c=0.0;
  for(int blk=t;blk<512;blk+=256){
    e += (double)ec[blk*4+0]+(double)ec[blk*4+1];
    c += (double)ec[blk*4+2]+(double)ec[blk*4+3];
  }
  red[t]=e; __syncthreads();
  for(int st=128;st>0;st>>=1){ if(t<st) red[t]+=red[t+st]; __syncthreads(); }
  double E=red[0]; __syncthreads();
  red[t]=c; __syncthreads();
  for(int st=128;st>0;st>>=1){ if(t<st) red[t]+=red[t+st]; __syncthreads(); }
  if(t==0){
    double C=red[0];
    double aux = 0.1*(E*(1.0/131072.0) - CB) + C*(1.0/1048576.0);
    auxout[0]=(float)aux;
  }
}

// ---------------- K4: decoder conv d1 (8->32, 3x3, pad1) on 64x64 ----------------
__global__ __launch_bounds__(256) void k_dec1(const float* __restrict__ q,
    const float* __restrict__ d1, const float* __restrict__ db1, float* __restrict__ out1)
{
  __shared__ float tile[8*342];   // [ic][18][19]
  const int b=blockIdx.z, r0=blockIdx.y*16, c0=blockIdx.x*16;
  const float* qp = q + (size_t)b*8*4096;
  for(int i=threadIdx.x;i<8*324;i+=256){
    int ic=i/324, rem=i-ic*324, r=rem/18, c=rem-r*18;
    int gr=r0+r-1, gc=c0+c-1;
    float v=0.f;
    if(gr>=0&&gr<64&&gc>=0&&gc<64) v=qp[ic*4096+gr*64+gc];
    tile[ic*342+r*19+c]=v;
  }
  __syncthreads();
  const int tx=threadIdx.x&15, ty=threadIdx.x>>4;
  float acc[32];
  #pragma unroll
  for(int o=0;o<32;o++) acc[o]=db1[o];
  #pragma unroll 2
  for(int ic=0;ic<8;ic++){
    float v[9];
    #pragma unroll
    for(int ky=0;ky<3;ky++)
      #pragma unroll
      for(int kx=0;kx<3;kx++)
        v[ky*3+kx]=tile[ic*342+(ty+ky)*19+tx+kx];
    #pragma unroll
    for(int o=0;o<32;o++){
      const float* wp=&d1[(o*8+ic)*9];
      float s=acc[o];
      #pragma unroll
      for(int kk=0;kk<9;kk++) s=fmaf(v[kk],wp[kk],s);
      acc[o]=s;
    }
  }
  float* op = out1 + (size_t)b*32*4096 + (r0+ty)*64 + (c0+tx);
  #pragma unroll
  for(int o=0;o<32;o++) op[(size_t)o*4096]=acc[o];
}

// ---------------- K5: upsample2 + conv d2 (32->16,3x3,pad1) + gelu, at 128-res ----------------
__global__ __launch_bounds__(256) void k_dec2(const float* __restrict__ out1,
    const float* __restrict__ wp4d2, const float* __restrict__ db2, float* __restrict__ out2)
{
  __shared__ float tile[32*342];   // [ic][18][19] src at 64-res
  const int b=blockIdx.z, y0=blockIdx.y*32, x0=blockIdx.x*32;
  const int sy0=(y0>>1)-1, sx0=(x0>>1)-1;
  const float* sp = out1 + (size_t)b*32*4096;
  for(int i=threadIdx.x;i<32*324;i+=256){
    int ic=i/324, rem=i-ic*324, r=rem/18, c=rem-r*18;
    int gr=sy0+r, gc=sx0+c;
    float v=0.f;
    if(gr>=0&&gr<64&&gc>=0&&gc<64) v=sp[ic*4096+gr*64+gc];
    tile[ic*342+r*19+c]=v;
  }
  __syncthreads();
  const int par=__builtin_amdgcn_readfirstlane((int)(threadIdx.x>>6));
  const int py=par>>1, px=par&1;
  const int l=threadIdx.x&63, r0l=l>>4, cl=l&15;
  const int bxl=cl+px;
  float acc[16][4];
  #pragma unroll
  for(int o=0;o<16;o++){
    float bv=db2[o];
    #pragma unroll
    for(int a=0;a<4;a++) acc[o][a]=bv;
  }
  #pragma unroll 2
  for(int ic=0;ic<32;ic++){
    const float* wq = wp4d2 + (size_t)((par*32+ic)*16)*4;   // 64 uniform floats
    float s00[4],s01[4],s10[4],s11[4];
    #pragma unroll
    for(int a=0;a<4;a++){
      const int byl=r0l+4*a+py;
      const float* tp=&tile[ic*342 + byl*19 + bxl];
      s00[a]=tp[0]; s01[a]=tp[1]; s10[a]=tp[19]; s11[a]=tp[20];
    }
    #pragma unroll
    for(int o=0;o<16;o++){
      const float wx=wq[o*4], wy=wq[o*4+1], wz=wq[o*4+2], ww=wq[o*4+3];
      #pragma unroll
      for(int a=0;a<4;a++)
        acc[o][a]=fmaf(s00[a],wx,fmaf(s01[a],wy,fmaf(s10[a],wz,fmaf(s11[a],ww,acc[o][a]))));
    }
  }
  #pragma unroll
  for(int o=0;o<16;o++){
    float* op = out2 + ((size_t)b*16+o)*16384;
    #pragma unroll
    for(int a=0;a<4;a++){
      const int yy=2*(r0l+4*a)+py, xx=2*cl+px;
      op[(size_t)(y0+yy)*128 + (x0+xx)] = gelu_exact(acc[o][a]);
    }
  }
}

// ---------------- K6: upsample2 + conv d3 (16->1,3x3,pad1) + clip, at 256-res ----------------
__global__ __launch_bounds__(256) void k_dec3(const float* __restrict__ out2,
    const float* __restrict__ d3, const float* __restrict__ db3, float* __restrict__ y)
{
  __shared__ float tile[16*342];   // [ic][18][19] src at 128-res
  __shared__ float4 wp4[64];       // [par*16+ic]
  const int b=blockIdx.z, y0=blockIdx.y*32, x0=blockIdx.x*32;
  const int sy0=(y0>>1)-1, sx0=(x0>>1)-1;
  const float* sp = out2 + (size_t)b*16*16384;
  for(int i=threadIdx.x;i<16*324;i+=256){
    int ic=i/324, rem=i-ic*324, r=rem/18, c=rem-r*18;
    int gr=sy0+r, gc=sx0+c;
    float v=0.f;
    if(gr>=0&&gr<128&&gc>=0&&gc<128) v=sp[ic*16384+gr*128+gc];
    tile[ic*342+r*19+c]=v;
  }
  if(threadIdx.x<64){
    int par=threadIdx.x>>4, ic=threadIdx.x&15;
    int py=par>>1, px=par&1;
    const float* wg = d3 + ic*9;
    float a00=0.f,a01=0.f,a10=0.f,a11=0.f;
    #pragma unroll
    for(int ky=0;ky<3;ky++){
      int sy = py ? (ky>>1) : ((ky>0)?1:0);
      #pragma unroll
      for(int kx=0;kx<3;kx++){
        int sx = px ? (kx>>1) : ((kx>0)?1:0);
        float wv=wg[ky*3+kx];
        if(sy==0){ if(sx==0)a00+=wv; else a01+=wv; }
        else     { if(sx==0)a10+=wv; else a11+=wv; }
      }
    }
    wp4[threadIdx.x]=make_float4(a00,a01,a10,a11);
  }
  __syncthreads();
  const float bias=db3[0];
  const int par=__builtin_amdgcn_readfirstlane((int)(threadIdx.x>>6));
  const int py=par>>1, px=par&1;
  const int l=threadIdx.x&63, r0l=l>>4, cl=l&15;
  const int bxl=cl+px;
  float acc[4];
  #pragma unroll
  for(int a=0;a<4;a++) acc[a]=bias;
  #pragma unroll 2
  for(int ic=0;ic<16;ic++){
    const float4 wv=wp4[par*16+ic];   // wave-uniform -> broadcast
    #pragma unroll
    for(int a=0;a<4;a++){
      const int byl=r0l+4*a+py;
      const float* tp=&tile[ic*342 + byl*19 + bxl];
      acc[a]=fmaf(tp[0],wv.x,fmaf(tp[1],wv.y,fmaf(tp[19],wv.z,fmaf(tp[20],wv.w,acc[a]))));
    }
  }
  #pragma unroll
  for(int a=0;a<4;a++){
    const int yy=2*(r0l+4*a)+py, xx=2*cl+px;
    float v=fminf(fmaxf(acc[a],-1.0f),1.0f);
    y[(size_t)b*65536 + (size_t)(y0+yy)*256 + (x0+xx)] = v;
  }
}

extern "C" void kernel_launch(void* const* d_in, const int* in_sizes, int n_in,
                              void* d_out, int out_size, void* d_ws, size_t ws_size,
                              hipStream_t stream)
{
  const float* x  =(const float*)d_in[0];
  const float* w1 =(const float*)d_in[1];
  const float* b1 =(const float*)d_in[2];
  const float* w2 =(const float*)d_in[3];
  const float* b2 =(const float*)d_in[4];
  const float* w3 =(const float*)d_in[5];
  const float* b3 =(const float*)d_in[6];
  const float* d1 =(const float*)d_in[7];
  const float* db1=(const float*)d_in[8];
  const float* d2 =(const float*)d_in[9];
  const float* db2=(const float*)d_in[10];
  const float* d3 =(const float*)d_in[11];
  const float* db3=(const float*)d_in[12];
  float* out=(float*)d_out;
  float* ws =(float*)d_ws;
  // ws layout (floats):
  // h1[8388608] | h2[4194304] | qb[1048576] | st[256] | avgp[262144] | ec[2048]
  // | wp4d2[8192] | avgs[512]
  // w2t (4608) aliases head of avgp (dead-time disjoint, stream-ordered).
  float* h1   = ws;
  float* h2   = ws + 8388608;
  float* qb   = ws + 12582912;
  float* st   = ws + 13631488;
  float* avgp = ws + 13631744;
  float* ec   = ws + 13893888;
  float* w2t  = avgp;
  float* wp4d2= ws + 13895936;
  float* avgs = ws + 13904128;
  float* out1 = h2;   // reuse: h2 dead after k_lfq
  float* out2 = h1;   // reuse: h1 dead after k_conv2

  k_prep <<<dim3(1),512,0,stream>>>(w2,d2,w2t,wp4d2);
  k_conv1<<<dim3(8,8,32),256,0,stream>>>(x,w1,b1,h1);
  k_conv2<<<dim3(8,8,32),256,0,stream>>>(h1,w2t,b2,h2);
  k_stats<<<dim3(128),256,0,stream>>>(h2,st);
  k_lfq  <<<dim3(512),256,0,stream>>>(h2,st,w3,b3,qb,out+2097152,avgp,ec);
  k_red  <<<dim3(32),256,0,stream>>>(avgp,avgs);
  k_final<<<dim3(1),256,0,stream>>>(avgs,ec,out+2359296);
  k_dec1 <<<dim3(4,4,32),256,0,stream>>>(qb,d1,db1,out1);
  k_dec2 <<<dim3(4,4,32),256,0,stream>>>(out1,wp4d2,db2,out2);
  k_dec3 <<<dim3(8,8,32),256,0,stream>>>(out2,d3,db3,out);
}

// Round 5
// 231.254 us; speedup vs baseline: 11.2918x; 1.1974x over previous
//
#include <hip/hip_runtime.h>
#include <hip/hip_bf16.h>
#include <math.h>

#define DEV __device__ __forceinline__

DEV float gelu_exact(float x){ return 0.5f*x*(1.0f + erff(x*0.70710678118654752f)); }

// ---------------- K0: prep — weight transpose / parity-combine tables ----------------
// w2t[(ic*32+oc)*9+k] ; wp4d2[((par*32+ic)*16+oc)*4+j]
__global__ __launch_bounds__(512) void k_prep(const float* __restrict__ w2,
    const float* __restrict__ d2, float* __restrict__ w2t, float* __restrict__ wp4d2)
{
  const int t=threadIdx.x;
  for(int i=t;i<4608;i+=512){
    int oc=i/144, rem=i-oc*144, ic=rem/9, k=rem-ic*9;
    w2t[(ic*32+oc)*9+k]=w2[i];
  }
  for(int i=t;i<2048;i+=512){
    int par=i>>9, ic=(i>>4)&31, oc=i&15;
    int py=par>>1, px=par&1;
    const float* wg = d2 + ((size_t)oc*32+ic)*9;
    float a00=0.f,a01=0.f,a10=0.f,a11=0.f;
    #pragma unroll
    for(int ky=0;ky<3;ky++){
      int sy = py ? (ky>>1) : ((ky>0)?1:0);
      #pragma unroll
      for(int kx=0;kx<3;kx++){
        int sx = px ? (kx>>1) : ((kx>0)?1:0);
        float wv=wg[ky*3+kx];
        if(sy==0){ if(sx==0)a00+=wv; else a01+=wv; }
        else     { if(sx==0)a10+=wv; else a11+=wv; }
      }
    }
    float* dst=wp4d2+(size_t)i*4;
    dst[0]=a00; dst[1]=a01; dst[2]=a10; dst[3]=a11;
  }
}

// ---------------- K1: conv1(1->16,3x3,pad1) + maxpool2 + gelu ----------------
// XCD-locality: x-tile = blockIdx.y (so x-neighbors share an XCD L2 -> col-halo reuse)
__global__ __launch_bounds__(256) void k_conv1(const float* __restrict__ x,
    const float* __restrict__ w1, const float* __restrict__ b1,
    float* __restrict__ h1)
{
  __shared__ float sE[34*19], sO[34*19];
  const int b = blockIdx.z;
  const int r0 = blockIdx.x*32, c0 = blockIdx.y*32;
  const float* xp = x + (size_t)b*65536;
  for(int i=threadIdx.x;i<34*34;i+=256){
    int r=i/34, c=i-r*34;
    int gr=r0+r-1, gc=c0+c-1;
    float v=0.f;
    if(gr>=0 && gr<256 && gc>=0 && gc<256) v = xp[gr*256+gc];
    if(c&1) sO[r*19+(c>>1)]=v; else sE[r*19+(c>>1)]=v;
  }
  __syncthreads();
  const int tx=threadIdx.x&15, ty=threadIdx.x>>4;
  const int base = 2*ty*19 + tx;
  float in[4][4];
  #pragma unroll
  for(int r=0;r<4;r++){
    in[r][0]=sE[base+r*19]; in[r][1]=sO[base+r*19];
    in[r][2]=sE[base+r*19+1]; in[r][3]=sO[base+r*19+1];
  }
  const int py = blockIdx.x*16+ty, px = blockIdx.y*16+tx;
  float* op = h1 + ((size_t)b*16)*16384 + py*128 + px;
  #pragma unroll
  for(int ch=0;ch<16;ch++){
    float m=-1e30f;
    #pragma unroll
    for(int pr=0;pr<2;pr++)
      #pragma unroll
      for(int pc=0;pc<2;pc++){
        float a=0.f;
        #pragma unroll
        for(int ky=0;ky<3;ky++)
          #pragma unroll
          for(int kx=0;kx<3;kx++)
            a = fmaf(in[pr+ky][pc+kx], w1[ch*9+ky*3+kx], a);
        m = fmaxf(m,a);
      }
    op[(size_t)ch*16384] = gelu_exact(m + b1[ch]);
  }
}

// ---------------- K2: conv2(16->32,3x3,pad1) + maxpool2 + groupnorm partials ----------------
// block 256 (4 waves x 8 oc = 4 GN groups); XCD-locality swap; per-wave f64 stats partials.
__global__ __launch_bounds__(256) void k_conv2(const float* __restrict__ h1,
    const float* __restrict__ w2t, const float* __restrict__ b2,
    float* __restrict__ h2, double* __restrict__ pb)
{
  __shared__ __align__(16) float t2[16*360];   // words [ic][18][20]
  const int b=blockIdx.z;
  const int r0=blockIdx.x*16, c0=blockIdx.y*16;  // unpooled origin (128-res)
  const float* hp = h1 + (size_t)b*16*16384;
  for(int i=threadIdx.x;i<2592;i+=256){
    int ic=i/162, rem=i-ic*162, lr=rem/9, jp=rem-lr*9;
    int gr=r0+lr-1, gc=c0+2*jp-1;
    float v0=0.f, v1=0.f;
    if(gr>=0&&gr<128){
      const float* row=hp+(size_t)ic*16384+(size_t)gr*128;
      if(gc>=0&&gc<128) v0=row[gc];
      if(gc+1<128)      v1=row[gc+1];
    }
    *(float2*)&t2[ic*360+lr*20+2*jp]=make_float2(v0,v1);
  }
  __syncthreads();
  const int pos=threadIdx.x&63;
  const int ocg=__builtin_amdgcn_readfirstlane((int)(threadIdx.x>>6));
  const int oc0=ocg*8;
  const int pyl=pos>>3, pxl=pos&7;
  const int base0 = 2*pyl*20 + 2*pxl;
  float acc[8][4];
  #pragma unroll
  for(int o=0;o<8;o++)
    #pragma unroll
    for(int j=0;j<4;j++) acc[o][j]=0.f;
  #pragma unroll 4
  for(int ic=0;ic<16;ic++){
    float in[4][4];
    #pragma unroll
    for(int r=0;r<4;r++){
      float2 a=*(const float2*)&t2[ic*360 + base0 + r*20];
      float2 c=*(const float2*)&t2[ic*360 + base0 + r*20 + 2];
      in[r][0]=a.x; in[r][1]=a.y; in[r][2]=c.x; in[r][3]=c.y;
    }
    const float* wp = w2t + (ic*32+oc0)*9;
    #pragma unroll
    for(int o=0;o<8;o++){
      #pragma unroll
      for(int pr=0;pr<2;pr++)
        #pragma unroll
        for(int pc=0;pc<2;pc++){
          float s=acc[o][pr*2+pc];
          #pragma unroll
          for(int ky=0;ky<3;ky++)
            #pragma unroll
            for(int kx=0;kx<3;kx++)
              s=fmaf(in[pr+ky][pc+kx], wp[o*9+ky*3+kx], s);
          acc[o][pr*2+pc]=s;
        }
    }
  }
  const int py=blockIdx.x*8+pyl, px=blockIdx.y*8+pxl;
  double s=0.0, s2=0.0;
  #pragma unroll
  for(int o=0;o<8;o++){
    const int oc=oc0+o;
    float m=fmaxf(fmaxf(acc[o][0],acc[o][1]),fmaxf(acc[o][2],acc[o][3]));
    float hv=m+b2[oc];
    h2[(((size_t)b*32+oc)*64+py)*64+px]=hv;
    s += (double)hv; s2 += (double)hv*(double)hv;
  }
  // wave butterfly reduce (deterministic) -> one partial per (block, group)
  #pragma unroll
  for(int off=32;off;off>>=1){
    s  += __shfl_xor(s,  off, 64);
    s2 += __shfl_xor(s2, off, 64);
  }
  if(pos==0){
    const int bidx = blockIdx.x*8 + blockIdx.y;
    double* p = pb + (((size_t)b*4+ocg)*64 + bidx)*2;
    p[0]=s; p[1]=s2;
  }
}

// ---------------- K2b: stats finalize (128 groups, f64, deterministic) ----------------
__global__ __launch_bounds__(64) void k_stats2(const double* __restrict__ pb,
                                               float* __restrict__ stats)
{
  const int bg=blockIdx.x, t=threadIdx.x;
  double s = pb[((size_t)bg*64+t)*2], s2 = pb[((size_t)bg*64+t)*2+1];
  #pragma unroll
  for(int off=32;off;off>>=1){
    s  += __shfl_xor(s,  off, 64);
    s2 += __shfl_xor(s2, off, 64);
  }
  if(t==0){
    double mu=s/32768.0;
    double var=s2/32768.0 - mu*mu;
    stats[bg]=(float)mu;
    stats[128+bg]=(float)(1.0/sqrt(var+1e-5));
  }
}

// ---------------- K3: groupnorm-apply + 1x1 conv + residual LFQ ----------------
// Phase-2: tabL/tabH [16][258]; b64 reads, bank-pair (jl+q)%16 -> conflict-free,
// 4-lane duplicates are same-address broadcasts (free).
__global__ __launch_bounds__(256) void k_lfq(const float* __restrict__ h2,
    const float* __restrict__ stats, const float* __restrict__ w3, const float* __restrict__ b3,
    float* __restrict__ qout, float* __restrict__ idxout,
    float* __restrict__ avgp, float* __restrict__ ec)
{
  __shared__ __align__(16) float tabL[16*258];
  __shared__ __align__(16) float tabH[16*258];
  const int blk=blockIdx.x;
  const int b=blk>>4;
  const int t=threadIdx.x;
  const int h=(blk&15)*4 + (t>>6);
  const int w=t&63;
  float mu[4], rs[4];
  #pragma unroll
  for(int g=0;g<4;g++){ mu[g]=stats[b*4+g]; rs[g]=stats[128+b*4+g]; }
  const float* hp = h2 + (size_t)b*131072 + h*64 + w;
  float z[8];
  #pragma unroll
  for(int d=0;d<8;d++) z[d]=b3[d];
  #pragma unroll
  for(int c=0;c<32;c++){
    float xn=(hp[(size_t)c*4096]-mu[c>>3])*rs[c>>3];
    #pragma unroll
    for(int d=0;d<8;d++) z[d]=fmaf(xn, w3[d*32+c], z[d]);
  }
  float r[8], qsum[8];
  #pragma unroll
  for(int d=0;d<8;d++){ r[d]=z[d]; qsum[d]=0.f; }
  float entk[2], comk[2];
  #pragma unroll
  for(int k=0;k<2;k++){
    int idx=0; float ent=0.f, com=0.f;
    float pb0[8], pb1[8];
    #pragma unroll
    for(int d=0;d<8;d++){
      float rv=r[d];
      bool pos = rv>0.f;
      float sgn = pos?1.f:-1.f;
      idx |= (pos?1:0)<<d;
      float dd=rv-sgn; com=fmaf(dd,dd,com);
      // Bernoulli factorization of the 256-way softmax; H = a(1-p) - ln p
      float a=400.f*fabsf(rv);
      float e=__expf(-a);
      float p=1.f/(1.f+e);
      ent += a - p*a - __logf(p);
      float pm=p, pq=1.f-p;
      pb1[d]=pos?pm:pq;
      pb0[d]=pos?pq:pm;
      qsum[d]+=sgn;
      r[d]=rv-sgn;
    }
    float lo[16], hi[16];
    lo[0]=pb0[0]; lo[1]=pb1[0];
    lo[2]=lo[0]*pb1[1]; lo[3]=lo[1]*pb1[1]; lo[0]*=pb0[1]; lo[1]*=pb0[1];
    lo[4]=lo[0]*pb1[2]; lo[5]=lo[1]*pb1[2]; lo[6]=lo[2]*pb1[2]; lo[7]=lo[3]*pb1[2];
    lo[0]*=pb0[2]; lo[1]*=pb0[2]; lo[2]*=pb0[2]; lo[3]*=pb0[2];
    lo[8]=lo[0]*pb1[3]; lo[9]=lo[1]*pb1[3]; lo[10]=lo[2]*pb1[3]; lo[11]=lo[3]*pb1[3];
    lo[12]=lo[4]*pb1[3]; lo[13]=lo[5]*pb1[3]; lo[14]=lo[6]*pb1[3]; lo[15]=lo[7]*pb1[3];
    lo[0]*=pb0[3]; lo[1]*=pb0[3]; lo[2]*=pb0[3]; lo[3]*=pb0[3];
    lo[4]*=pb0[3]; lo[5]*=pb0[3]; lo[6]*=pb0[3]; lo[7]*=pb0[3];
    hi[0]=pb0[4]; hi[1]=pb1[4];
    hi[2]=hi[0]*pb1[5]; hi[3]=hi[1]*pb1[5]; hi[0]*=pb0[5]; hi[1]*=pb0[5];
    hi[4]=hi[0]*pb1[6]; hi[5]=hi[1]*pb1[6]; hi[6]=hi[2]*pb1[6]; hi[7]=hi[3]*pb1[6];
    hi[0]*=pb0[6]; hi[1]*=pb0[6]; hi[2]*=pb0[6]; hi[3]*=pb0[6];
    hi[8]=hi[0]*pb1[7]; hi[9]=hi[1]*pb1[7]; hi[10]=hi[2]*pb1[7]; hi[11]=hi[3]*pb1[7];
    hi[12]=hi[4]*pb1[7]; hi[13]=hi[5]*pb1[7]; hi[14]=hi[6]*pb1[7]; hi[15]=hi[7]*pb1[7];
    hi[0]*=pb0[7]; hi[1]*=pb0[7]; hi[2]*=pb0[7]; hi[3]*=pb0[7];
    hi[4]*=pb0[7]; hi[5]*=pb0[7]; hi[6]*=pb0[7]; hi[7]*=pb0[7];
    #pragma unroll
    for(int m=0;m<16;m++){ tabL[m*258+t]=lo[m]; tabH[m*258+t]=hi[m]; }
    __syncthreads();
    // phase 2: thread t owns code (jh,jl); float2 over tokens, conflict-free
    float accp=0.f, accq=0.f;
    const int jl=t&15, jh=t>>4;
    const float* Lp=&tabL[jl*258];
    const float* Hp=&tabH[jh*258];
    #pragma unroll 8
    for(int q=0;q<128;q++){
      float2 L=*(const float2*)&Lp[2*q];
      float2 H=*(const float2*)&Hp[2*q];
      accp=fmaf(L.x,H.x,accp); accq=fmaf(L.y,H.y,accq);
    }
    avgp[((size_t)k*512+blk)*256+t]=accp+accq;
    __syncthreads();
    entk[k]=ent; comk[k]=com;
    idxout[((size_t)(b*64+h)*64+w)*2+k]=(float)idx;
  }
  #pragma unroll
  for(int d=0;d<8;d++)
    qout[(((size_t)b*8+d)*64+h)*64+w]=qsum[d];
  tabL[t]=entk[0]; tabL[256+t]=entk[1]; tabL[512+t]=comk[0]; tabL[768+t]=comk[1];
  __syncthreads();
  for(int st=128;st>0;st>>=1){
    if(t<st){ tabL[t]+=tabL[t+st]; tabL[256+t]+=tabL[256+t+st];
              tabL[512+t]+=tabL[512+t+st]; tabL[768+t]+=tabL[768+t+st]; }
    __syncthreads();
  }
  if(t==0){ ec[blk*4+0]=tabL[0]; ec[blk*4+1]=tabL[256]; ec[blk*4+2]=tabL[512]; ec[blk*4+3]=tabL[768]; }
}

// ---------------- K3r: parallel avgp reduction (32 blocks) ----------------
__global__ __launch_bounds__(256) void k_red(const float* __restrict__ avgp,
    float* __restrict__ avgs)
{
  const int k=blockIdx.x>>4, c0=(blockIdx.x&15)*16;
  const int col=threadIdx.x&15, rg=threadIdx.x>>4;
  float s=0.f;
  for(int j=0;j<32;j++){
    int blk=rg+16*j;
    s+=avgp[((size_t)k*512+blk)*256+c0+col];
  }
  __shared__ float red[256];
  red[threadIdx.x]=s; __syncthreads();
  for(int st=128;st>=16;st>>=1){
    if(threadIdx.x<st) red[threadIdx.x]+=red[threadIdx.x+st];
    __syncthreads();
  }
  if(threadIdx.x<16) avgs[k*256+c0+threadIdx.x]=red[threadIdx.x];
}

// ---------------- K3b: final aux (1 block, deterministic, f64) ----------------
__global__ __launch_bounds__(256) void k_final(const float* __restrict__ avgs,
    const float* __restrict__ ec, float* __restrict__ auxout)
{
  __shared__ double red[256];
  const int t=threadIdx.x;
  double cb=0.0;
  #pragma unroll
  for(int k=0;k<2;k++){
    double ap=(double)avgs[k*256+t]*(1.0/131072.0);
    cb += -(ap*log(ap+1e-10));
  }
  red[t]=cb; __syncthreads();
  for(int st=128;st>0;st>>=1){ if(t<st) red[t]+=red[t+st]; __syncthreads(); }
  double CB=red[0]; __syncthreads();
  double e=0.0,c=0.0;
  for(int blk=t;blk<512;blk+=256){
    e += (double)ec[blk*4+0]+(double)ec[blk*4+1];
    c += (double)ec[blk*4+2]+(double)ec[blk*4+3];
  }
  red[t]=e; __syncthreads();
  for(int st=128;st>0;st>>=1){ if(t<st) red[t]+=red[t+st]; __syncthreads(); }
  double E=red[0]; __syncthreads();
  red[t]=c; __syncthreads();
  for(int st=128;st>0;st>>=1){ if(t<st) red[t]+=red[t+st]; __syncthreads(); }
  if(t==0){
    double C=red[0];
    double aux = 0.1*(E*(1.0/131072.0) - CB) + C*(1.0/1048576.0);
    auxout[0]=(float)aux;
  }
}

// ---------------- K4: decoder conv d1 (8->32, 3x3, pad1) on 64x64 ----------------
__global__ __launch_bounds__(256) void k_dec1(const float* __restrict__ q,
    const float* __restrict__ d1, const float* __restrict__ db1, float* __restrict__ out1)
{
  __shared__ float tile[8*342];   // [ic][18][19]
  const int b=blockIdx.z, r0=blockIdx.y*16, c0=blockIdx.x*16;
  const float* qp = q + (size_t)b*8*4096;
  for(int i=threadIdx.x;i<8*324;i+=256){
    int ic=i/324, rem=i-ic*324, r=rem/18, c=rem-r*18;
    int gr=r0+r-1, gc=c0+c-1;
    float v=0.f;
    if(gr>=0&&gr<64&&gc>=0&&gc<64) v=qp[ic*4096+gr*64+gc];
    tile[ic*342+r*19+c]=v;
  }
  __syncthreads();
  const int tx=threadIdx.x&15, ty=threadIdx.x>>4;
  float acc[32];
  #pragma unroll
  for(int o=0;o<32;o++) acc[o]=db1[o];
  #pragma unroll 2
  for(int ic=0;ic<8;ic++){
    float v[9];
    #pragma unroll
    for(int ky=0;ky<3;ky++)
      #pragma unroll
      for(int kx=0;kx<3;kx++)
        v[ky*3+kx]=tile[ic*342+(ty+ky)*19+tx+kx];
    #pragma unroll
    for(int o=0;o<32;o++){
      const float* wp=&d1[(o*8+ic)*9];
      float s=acc[o];
      #pragma unroll
      for(int kk=0;kk<9;kk++) s=fmaf(v[kk],wp[kk],s);
      acc[o]=s;
    }
  }
  float* op = out1 + (size_t)b*32*4096 + (r0+ty)*64 + (c0+tx);
  #pragma unroll
  for(int o=0;o<32;o++) op[(size_t)o*4096]=acc[o];
}

// ---------------- K5: upsample2 + conv d2 (32->16,3x3,pad1) + gelu, at 128-res ----------------
__global__ __launch_bounds__(256) void k_dec2(const float* __restrict__ out1,
    const float* __restrict__ wp4d2, const float* __restrict__ db2, float* __restrict__ out2)
{
  __shared__ float tile[32*342];   // [ic][18][19] src at 64-res
  const int b=blockIdx.z, y0=blockIdx.y*32, x0=blockIdx.x*32;
  const int sy0=(y0>>1)-1, sx0=(x0>>1)-1;
  const float* sp = out1 + (size_t)b*32*4096;
  for(int i=threadIdx.x;i<32*324;i+=256){
    int ic=i/324, rem=i-ic*324, r=rem/18, c=rem-r*18;
    int gr=sy0+r, gc=sx0+c;
    float v=0.f;
    if(gr>=0&&gr<64&&gc>=0&&gc<64) v=sp[ic*4096+gr*64+gc];
    tile[ic*342+r*19+c]=v;
  }
  __syncthreads();
  const int par=__builtin_amdgcn_readfirstlane((int)(threadIdx.x>>6));
  const int py=par>>1, px=par&1;
  const int l=threadIdx.x&63, r0l=l>>4, cl=l&15;
  const int bxl=cl+px;
  float acc[16][4];
  #pragma unroll
  for(int o=0;o<16;o++){
    float bv=db2[o];
    #pragma unroll
    for(int a=0;a<4;a++) acc[o][a]=bv;
  }
  #pragma unroll 2
  for(int ic=0;ic<32;ic++){
    const float* wq = wp4d2 + (size_t)((par*32+ic)*16)*4;   // 64 uniform floats
    float s00[4],s01[4],s10[4],s11[4];
    #pragma unroll
    for(int a=0;a<4;a++){
      const int byl=r0l+4*a+py;
      const float* tp=&tile[ic*342 + byl*19 + bxl];
      s00[a]=tp[0]; s01[a]=tp[1]; s10[a]=tp[19]; s11[a]=tp[20];
    }
    #pragma unroll
    for(int o=0;o<16;o++){
      const float wx=wq[o*4], wy=wq[o*4+1], wz=wq[o*4+2], ww=wq[o*4+3];
      #pragma unroll
      for(int a=0;a<4;a++)
        acc[o][a]=fmaf(s00[a],wx,fmaf(s01[a],wy,fmaf(s10[a],wz,fmaf(s11[a],ww,acc[o][a]))));
    }
  }
  #pragma unroll
  for(int o=0;o<16;o++){
    float* op = out2 + ((size_t)b*16+o)*16384;
    #pragma unroll
    for(int a=0;a<4;a++){
      const int yy=2*(r0l+4*a)+py, xx=2*cl+px;
      op[(size_t)(y0+yy)*128 + (x0+xx)] = gelu_exact(acc[o][a]);
    }
  }
}

// ---------------- K6: upsample2 + conv d3 (16->1,3x3,pad1) + clip, at 256-res ----------------
// XCD-locality swap: x-tile = blockIdx.y
__global__ __launch_bounds__(256) void k_dec3(const float* __restrict__ out2,
    const float* __restrict__ d3, const float* __restrict__ db3, float* __restrict__ y)
{
  __shared__ float tile[16*342];   // [ic][18][19] src at 128-res
  __shared__ float4 wp4[64];       // [par*16+ic]
  const int b=blockIdx.z, y0=blockIdx.x*32, x0=blockIdx.y*32;
  const int sy0=(y0>>1)-1, sx0=(x0>>1)-1;
  const float* sp = out2 + (size_t)b*16*16384;
  for(int i=threadIdx.x;i<16*324;i+=256){
    int ic=i/324, rem=i-ic*324, r=rem/18, c=rem-r*18;
    int gr=sy0+r, gc=sx0+c;
    float v=0.f;
    if(gr>=0&&gr<128&&gc>=0&&gc<128) v=sp[ic*16384+gr*128+gc];
    tile[ic*342+r*19+c]=v;
  }
  if(threadIdx.x<64){
    int par=threadIdx.x>>4, ic=threadIdx.x&15;
    int py=par>>1, px=par&1;
    const float* wg = d3 + ic*9;
    float a00=0.f,a01=0.f,a10=0.f,a11=0.f;
    #pragma unroll
    for(int ky=0;ky<3;ky++){
      int sy = py ? (ky>>1) : ((ky>0)?1:0);
      #pragma unroll
      for(int kx=0;kx<3;kx++){
        int sx = px ? (kx>>1) : ((kx>0)?1:0);
        float wv=wg[ky*3+kx];
        if(sy==0){ if(sx==0)a00+=wv; else a01+=wv; }
        else     { if(sx==0)a10+=wv; else a11+=wv; }
      }
    }
    wp4[threadIdx.x]=make_float4(a00,a01,a10,a11);
  }
  __syncthreads();
  const float bias=db3[0];
  const int par=__builtin_amdgcn_readfirstlane((int)(threadIdx.x>>6));
  const int py=par>>1, px=par&1;
  const int l=threadIdx.x&63, r0l=l>>4, cl=l&15;
  const int bxl=cl+px;
  float acc[4];
  #pragma unroll
  for(int a=0;a<4;a++) acc[a]=bias;
  #pragma unroll 2
  for(int ic=0;ic<16;ic++){
    const float4 wv=wp4[par*16+ic];   // wave-uniform -> broadcast
    #pragma unroll
    for(int a=0;a<4;a++){
      const int byl=r0l+4*a+py;
      const float* tp=&tile[ic*342 + byl*19 + bxl];
      acc[a]=fmaf(tp[0],wv.x,fmaf(tp[1],wv.y,fmaf(tp[19],wv.z,fmaf(tp[20],wv.w,acc[a]))));
    }
  }
  #pragma unroll
  for(int a=0;a<4;a++){
    const int yy=2*(r0l+4*a)+py, xx=2*cl+px;
    float v=fminf(fmaxf(acc[a],-1.0f),1.0f);
    y[(size_t)b*65536 + (size_t)(y0+yy)*256 + (x0+xx)] = v;
  }
}

extern "C" void kernel_launch(void* const* d_in, const int* in_sizes, int n_in,
                              void* d_out, int out_size, void* d_ws, size_t ws_size,
                              hipStream_t stream)
{
  const float* x  =(const float*)d_in[0];
  const float* w1 =(const float*)d_in[1];
  const float* b1 =(const float*)d_in[2];
  const float* w2 =(const float*)d_in[3];
  const float* b2 =(const float*)d_in[4];
  const float* w3 =(const float*)d_in[5];
  const float* b3 =(const float*)d_in[6];
  const float* d1 =(const float*)d_in[7];
  const float* db1=(const float*)d_in[8];
  const float* d2 =(const float*)d_in[9];
  const float* db2=(const float*)d_in[10];
  const float* d3 =(const float*)d_in[11];
  const float* db3=(const float*)d_in[12];
  float* out=(float*)d_out;
  float* ws =(float*)d_ws;
  // ws layout (floats):
  // h1[8388608] | h2[4194304] | qb[1048576] | st[256] | avgp[262144] | ec[2048]
  // | wp4d2[8192] | avgs[512]
  // Aliases (stream-order disjoint):
  //   w2t (4608 fl) = head of avgp   (prep->conv2, then lfq overwrites)
  //   pb  (16384 doubles = 128KB) = qb region (conv2->stats2, then lfq writes qb)
  //   out1 = h2 (dead after lfq) ; out2 = h1 (dead after conv2)
  float* h1   = ws;
  float* h2   = ws + 8388608;
  float* qb   = ws + 12582912;
  float* st   = ws + 13631488;
  float* avgp = ws + 13631744;
  float* ec   = ws + 13893888;
  float* w2t  = avgp;
  float* wp4d2= ws + 13895936;
  float* avgs = ws + 13904128;
  double* pb  = (double*)qb;
  float* out1 = h2;
  float* out2 = h1;

  k_prep  <<<dim3(1),512,0,stream>>>(w2,d2,w2t,wp4d2);
  k_conv1 <<<dim3(8,8,32),256,0,stream>>>(x,w1,b1,h1);
  k_conv2 <<<dim3(8,8,32),256,0,stream>>>(h1,w2t,b2,h2,pb);
  k_stats2<<<dim3(128),64,0,stream>>>(pb,st);
  k_lfq   <<<dim3(512),256,0,stream>>>(h2,st,w3,b3,qb,out+2097152,avgp,ec);
  k_red   <<<dim3(32),256,0,stream>>>(avgp,avgs);
  k_final <<<dim3(1),256,0,stream>>>(avgs,ec,out+2359296);
  k_dec1  <<<dim3(4,4,32),256,0,stream>>>(qb,d1,db1,out1);
  k_dec2  <<<dim3(4,4,32),256,0,stream>>>(out1,wp4d2,db2,out2);
  k_dec3  <<<dim3(8,8,32),256,0,stream>>>(out2,d3,db3,out);
}

// Round 6
// 202.312 us; speedup vs baseline: 12.9072x; 1.1431x over previous
//
#include <hip/hip_runtime.h>
#include <hip/hip_bf16.h>
#include <math.h>

#define DEV __device__ __forceinline__

DEV float gelu_exact(float x){ return 0.5f*x*(1.0f + erff(x*0.70710678118654752f)); }

// ---------------- K0: prep — weight transpose / parity-combine tables ----------------
// w2t[(ic*32+oc)*9+k] ; wp4d2[((par*32+ic)*16+oc)*4+j] ; grid 8 x 256
__global__ __launch_bounds__(256) void k_prep(const float* __restrict__ w2,
    const float* __restrict__ d2, float* __restrict__ w2t, float* __restrict__ wp4d2)
{
  const int gid = blockIdx.x*256 + threadIdx.x;
  for(int i=gid;i<4608;i+=2048){
    int oc=i/144, rem=i-oc*144, ic=rem/9, k=rem-ic*9;
    w2t[(ic*32+oc)*9+k]=w2[i];
  }
  for(int i=gid;i<2048;i+=2048){
    int par=i>>9, ic=(i>>4)&31, oc=i&15;
    int py=par>>1, px=par&1;
    const float* wg = d2 + ((size_t)oc*32+ic)*9;
    float a00=0.f,a01=0.f,a10=0.f,a11=0.f;
    #pragma unroll
    for(int ky=0;ky<3;ky++){
      int sy = py ? (ky>>1) : ((ky>0)?1:0);
      #pragma unroll
      for(int kx=0;kx<3;kx++){
        int sx = px ? (kx>>1) : ((kx>0)?1:0);
        float wv=wg[ky*3+kx];
        if(sy==0){ if(sx==0)a00+=wv; else a01+=wv; }
        else     { if(sx==0)a10+=wv; else a11+=wv; }
      }
    }
    float* dst=wp4d2+(size_t)i*4;
    dst[0]=a00; dst[1]=a01; dst[2]=a10; dst[3]=a11;
  }
}

// ---------------- K1: conv1(1->16,3x3,pad1) + maxpool2 + gelu ----------------
// XCD-locality: x-tile = blockIdx.y
__global__ __launch_bounds__(256) void k_conv1(const float* __restrict__ x,
    const float* __restrict__ w1, const float* __restrict__ b1,
    float* __restrict__ h1)
{
  __shared__ float sE[34*19], sO[34*19];
  const int b = blockIdx.z;
  const int r0 = blockIdx.x*32, c0 = blockIdx.y*32;
  const float* xp = x + (size_t)b*65536;
  for(int i=threadIdx.x;i<34*34;i+=256){
    int r=i/34, c=i-r*34;
    int gr=r0+r-1, gc=c0+c-1;
    float v=0.f;
    if(gr>=0 && gr<256 && gc>=0 && gc<256) v = xp[gr*256+gc];
    if(c&1) sO[r*19+(c>>1)]=v; else sE[r*19+(c>>1)]=v;
  }
  __syncthreads();
  const int tx=threadIdx.x&15, ty=threadIdx.x>>4;
  const int base = 2*ty*19 + tx;
  float in[4][4];
  #pragma unroll
  for(int r=0;r<4;r++){
    in[r][0]=sE[base+r*19]; in[r][1]=sO[base+r*19];
    in[r][2]=sE[base+r*19+1]; in[r][3]=sO[base+r*19+1];
  }
  const int py = blockIdx.x*16+ty, px = blockIdx.y*16+tx;
  float* op = h1 + ((size_t)b*16)*16384 + py*128 + px;
  #pragma unroll
  for(int ch=0;ch<16;ch++){
    float m=-1e30f;
    #pragma unroll
    for(int pr=0;pr<2;pr++)
      #pragma unroll
      for(int pc=0;pc<2;pc++){
        float a=0.f;
        #pragma unroll
        for(int ky=0;ky<3;ky++)
          #pragma unroll
          for(int kx=0;kx<3;kx++)
            a = fmaf(in[pr+ky][pc+kx], w1[ch*9+ky*3+kx], a);
        m = fmaxf(m,a);
      }
    op[(size_t)ch*16384] = gelu_exact(m + b1[ch]);
  }
}

// ---------------- K2: conv2(16->32,3x3,pad1) + maxpool2 + groupnorm partials ----------------
// Split-ic staging: LDS [8][18][20] = 11.5 KB -> 8 blocks/CU resident (full grid).
__global__ __launch_bounds__(256) void k_conv2(const float* __restrict__ h1,
    const float* __restrict__ w2t, const float* __restrict__ b2,
    float* __restrict__ h2, double* __restrict__ pb)
{
  __shared__ __align__(16) float t2[8*360];   // words [ic][18][20]
  const int b=blockIdx.z;
  const int r0=blockIdx.x*16, c0=blockIdx.y*16;  // unpooled origin (128-res)
  const float* hp = h1 + (size_t)b*16*16384;
  const int pos=threadIdx.x&63;
  const int ocg=__builtin_amdgcn_readfirstlane((int)(threadIdx.x>>6));
  const int oc0=ocg*8;
  const int pyl=pos>>3, pxl=pos&7;
  const int base0 = 2*pyl*20 + 2*pxl;
  float acc[8][4];
  #pragma unroll
  for(int o=0;o<8;o++)
    #pragma unroll
    for(int j=0;j<4;j++) acc[o][j]=0.f;

  for(int half=0;half<2;half++){
    for(int i=threadIdx.x;i<1296;i+=256){
      int ic=i/162, rem=i-ic*162, lr=rem/9, jp=rem-lr*9;
      int gr=r0+lr-1, gc=c0+2*jp-1;
      float v0=0.f, v1=0.f;
      if(gr>=0&&gr<128){
        const float* row=hp+(size_t)(half*8+ic)*16384+(size_t)gr*128;
        if(gc>=0&&gc<128) v0=row[gc];
        if(gc+1<128)      v1=row[gc+1];
      }
      *(float2*)&t2[ic*360+lr*20+2*jp]=make_float2(v0,v1);
    }
    __syncthreads();
    #pragma unroll 4
    for(int ic=0;ic<8;ic++){
      float in[4][4];
      #pragma unroll
      for(int r=0;r<4;r++){
        float2 a=*(const float2*)&t2[ic*360 + base0 + r*20];
        float2 c=*(const float2*)&t2[ic*360 + base0 + r*20 + 2];
        in[r][0]=a.x; in[r][1]=a.y; in[r][2]=c.x; in[r][3]=c.y;
      }
      const float* wp = w2t + ((half*8+ic)*32+oc0)*9;
      #pragma unroll
      for(int o=0;o<8;o++){
        #pragma unroll
        for(int pr=0;pr<2;pr++)
          #pragma unroll
          for(int pc=0;pc<2;pc++){
            float s=acc[o][pr*2+pc];
            #pragma unroll
            for(int ky=0;ky<3;ky++)
              #pragma unroll
              for(int kx=0;kx<3;kx++)
                s=fmaf(in[pr+ky][pc+kx], wp[o*9+ky*3+kx], s);
            acc[o][pr*2+pc]=s;
          }
      }
    }
    __syncthreads();
  }
  const int py=blockIdx.x*8+pyl, px=blockIdx.y*8+pxl;
  double s=0.0, s2=0.0;
  #pragma unroll
  for(int o=0;o<8;o++){
    const int oc=oc0+o;
    float m=fmaxf(fmaxf(acc[o][0],acc[o][1]),fmaxf(acc[o][2],acc[o][3]));
    float hv=m+b2[oc];
    h2[(((size_t)b*32+oc)*64+py)*64+px]=hv;
    s += (double)hv; s2 += (double)hv*(double)hv;
  }
  #pragma unroll
  for(int off=32;off;off>>=1){
    s  += __shfl_xor(s,  off, 64);
    s2 += __shfl_xor(s2, off, 64);
  }
  if(pos==0){
    const int bidx = blockIdx.x*8 + blockIdx.y;
    double* p = pb + (((size_t)b*4+ocg)*64 + bidx)*2;
    p[0]=s; p[1]=s2;
  }
}

// ---------------- K2b: stats finalize (128 groups, f64, deterministic) ----------------
__global__ __launch_bounds__(64) void k_stats2(const double* __restrict__ pb,
                                               float* __restrict__ stats)
{
  const int bg=blockIdx.x, t=threadIdx.x;
  double s = pb[((size_t)bg*64+t)*2], s2 = pb[((size_t)bg*64+t)*2+1];
  #pragma unroll
  for(int off=32;off;off>>=1){
    s  += __shfl_xor(s,  off, 64);
    s2 += __shfl_xor(s2, off, 64);
  }
  if(t==0){
    double mu=s/32768.0;
    double var=s2/32768.0 - mu*mu;
    stats[bg]=(float)mu;
    stats[128+bg]=(float)(1.0/sqrt(var+1e-5));
  }
}

// ---------------- K3: groupnorm-apply + 1x1 conv + residual LFQ ----------------
__global__ __launch_bounds__(256) void k_lfq(const float* __restrict__ h2,
    const float* __restrict__ stats, const float* __restrict__ w3, const float* __restrict__ b3,
    float* __restrict__ qout, float* __restrict__ idxout,
    float* __restrict__ avgp, float* __restrict__ ec)
{
  __shared__ __align__(16) float tabL[16*258];
  __shared__ __align__(16) float tabH[16*258];
  const int blk=blockIdx.x;
  const int b=blk>>4;
  const int t=threadIdx.x;
  const int h=(blk&15)*4 + (t>>6);
  const int w=t&63;
  float mu[4], rs[4];
  #pragma unroll
  for(int g=0;g<4;g++){ mu[g]=stats[b*4+g]; rs[g]=stats[128+b*4+g]; }
  const float* hp = h2 + (size_t)b*131072 + h*64 + w;
  float z[8];
  #pragma unroll
  for(int d=0;d<8;d++) z[d]=b3[d];
  #pragma unroll
  for(int c=0;c<32;c++){
    float xn=(hp[(size_t)c*4096]-mu[c>>3])*rs[c>>3];
    #pragma unroll
    for(int d=0;d<8;d++) z[d]=fmaf(xn, w3[d*32+c], z[d]);
  }
  float r[8], qsum[8];
  #pragma unroll
  for(int d=0;d<8;d++){ r[d]=z[d]; qsum[d]=0.f; }
  float entk[2], comk[2];
  #pragma unroll
  for(int k=0;k<2;k++){
    int idx=0; float ent=0.f, com=0.f;
    float pb0[8], pb1[8];
    #pragma unroll
    for(int d=0;d<8;d++){
      float rv=r[d];
      bool pos = rv>0.f;
      float sgn = pos?1.f:-1.f;
      idx |= (pos?1:0)<<d;
      float dd=rv-sgn; com=fmaf(dd,dd,com);
      float a=400.f*fabsf(rv);
      float e=__expf(-a);
      float p=1.f/(1.f+e);
      ent += a - p*a - __logf(p);
      float pm=p, pq=1.f-p;
      pb1[d]=pos?pm:pq;
      pb0[d]=pos?pq:pm;
      qsum[d]+=sgn;
      r[d]=rv-sgn;
    }
    float lo[16], hi[16];
    lo[0]=pb0[0]; lo[1]=pb1[0];
    lo[2]=lo[0]*pb1[1]; lo[3]=lo[1]*pb1[1]; lo[0]*=pb0[1]; lo[1]*=pb0[1];
    lo[4]=lo[0]*pb1[2]; lo[5]=lo[1]*pb1[2]; lo[6]=lo[2]*pb1[2]; lo[7]=lo[3]*pb1[2];
    lo[0]*=pb0[2]; lo[1]*=pb0[2]; lo[2]*=pb0[2]; lo[3]*=pb0[2];
    lo[8]=lo[0]*pb1[3]; lo[9]=lo[1]*pb1[3]; lo[10]=lo[2]*pb1[3]; lo[11]=lo[3]*pb1[3];
    lo[12]=lo[4]*pb1[3]; lo[13]=lo[5]*pb1[3]; lo[14]=lo[6]*pb1[3]; lo[15]=lo[7]*pb1[3];
    lo[0]*=pb0[3]; lo[1]*=pb0[3]; lo[2]*=pb0[3]; lo[3]*=pb0[3];
    lo[4]*=pb0[3]; lo[5]*=pb0[3]; lo[6]*=pb0[3]; lo[7]*=pb0[3];
    hi[0]=pb0[4]; hi[1]=pb1[4];
    hi[2]=hi[0]*pb1[5]; hi[3]=hi[1]*pb1[5]; hi[0]*=pb0[5]; hi[1]*=pb0[5];
    hi[4]=hi[0]*pb1[6]; hi[5]=hi[1]*pb1[6]; hi[6]=hi[2]*pb1[6]; hi[7]=hi[3]*pb1[6];
    hi[0]*=pb0[6]; hi[1]*=pb0[6]; hi[2]*=pb0[6]; hi[3]*=pb0[6];
    hi[8]=hi[0]*pb1[7]; hi[9]=hi[1]*pb1[7]; hi[10]=hi[2]*pb1[7]; hi[11]=hi[3]*pb1[7];
    hi[12]=hi[4]*pb1[7]; hi[13]=hi[5]*pb1[7]; hi[14]=hi[6]*pb1[7]; hi[15]=hi[7]*pb1[7];
    hi[0]*=pb0[7]; hi[1]*=pb0[7]; hi[2]*=pb0[7]; hi[3]*=pb0[7];
    hi[4]*=pb0[7]; hi[5]*=pb0[7]; hi[6]*=pb0[7]; hi[7]*=pb0[7];
    #pragma unroll
    for(int m=0;m<16;m++){ tabL[m*258+t]=lo[m]; tabH[m*258+t]=hi[m]; }
    __syncthreads();
    float accp=0.f, accq=0.f;
    const int jl=t&15, jh=t>>4;
    const float* Lp=&tabL[jl*258];
    const float* Hp=&tabH[jh*258];
    #pragma unroll 8
    for(int q=0;q<128;q++){
      float2 L=*(const float2*)&Lp[2*q];
      float2 H=*(const float2*)&Hp[2*q];
      accp=fmaf(L.x,H.x,accp); accq=fmaf(L.y,H.y,accq);
    }
    avgp[((size_t)k*512+blk)*256+t]=accp+accq;
    __syncthreads();
    entk[k]=ent; comk[k]=com;
    idxout[((size_t)(b*64+h)*64+w)*2+k]=(float)idx;
  }
  #pragma unroll
  for(int d=0;d<8;d++)
    qout[(((size_t)b*8+d)*64+h)*64+w]=qsum[d];
  tabL[t]=entk[0]; tabL[256+t]=entk[1]; tabL[512+t]=comk[0]; tabL[768+t]=comk[1];
  __syncthreads();
  for(int st=128;st>0;st>>=1){
    if(t<st){ tabL[t]+=tabL[t+st]; tabL[256+t]+=tabL[256+t+st];
              tabL[512+t]+=tabL[512+t+st]; tabL[768+t]+=tabL[768+t+st]; }
    __syncthreads();
  }
  if(t==0){ ec[blk*4+0]=tabL[0]; ec[blk*4+1]=tabL[256]; ec[blk*4+2]=tabL[512]; ec[blk*4+3]=tabL[768]; }
}

// ---------------- K3r: parallel avgp reduction (32 blocks) ----------------
__global__ __launch_bounds__(256) void k_red(const float* __restrict__ avgp,
    float* __restrict__ avgs)
{
  const int k=blockIdx.x>>4, c0=(blockIdx.x&15)*16;
  const int col=threadIdx.x&15, rg=threadIdx.x>>4;
  float s=0.f;
  for(int j=0;j<32;j++){
    int blk=rg+16*j;
    s+=avgp[((size_t)k*512+blk)*256+c0+col];
  }
  __shared__ float red[256];
  red[threadIdx.x]=s; __syncthreads();
  for(int st=128;st>=16;st>>=1){
    if(threadIdx.x<st) red[threadIdx.x]+=red[threadIdx.x+st];
    __syncthreads();
  }
  if(threadIdx.x<16) avgs[k*256+c0+threadIdx.x]=red[threadIdx.x];
}

// ---------------- K3b: final aux (1 block, deterministic, f64) ----------------
__global__ __launch_bounds__(256) void k_final(const float* __restrict__ avgs,
    const float* __restrict__ ec, float* __restrict__ auxout)
{
  __shared__ double red[256];
  const int t=threadIdx.x;
  double cb=0.0;
  #pragma unroll
  for(int k=0;k<2;k++){
    double ap=(double)avgs[k*256+t]*(1.0/131072.0);
    cb += -(ap*log(ap+1e-10));
  }
  red[t]=cb; __syncthreads();
  for(int st=128;st>0;st>>=1){ if(t<st) red[t]+=red[t+st]; __syncthreads(); }
  double CB=red[0]; __syncthreads();
  double e=0.0,c=0.0;
  for(int blk=t;blk<512;blk+=256){
    e += (double)ec[blk*4+0]+(double)ec[blk*4+1];
    c += (double)ec[blk*4+2]+(double)ec[blk*4+3];
  }
  red[t]=e; __syncthreads();
  for(int st=128;st>0;st>>=1){ if(t<st) red[t]+=red[t+st]; __syncthreads(); }
  double E=red[0]; __syncthreads();
  red[t]=c; __syncthreads();
  for(int st=128;st>0;st>>=1){ if(t<st) red[t]+=red[t+st]; __syncthreads(); }
  if(t==0){
    double C=red[0];
    double aux = 0.1*(E*(1.0/131072.0) - CB) + C*(1.0/1048576.0);
    auxout[0]=(float)aux;
  }
}

// ---------------- K4: decoder conv d1 (8->32, 3x3, pad1) on 64x64 ----------------
// grid (8,8,32): 8x8 tiles, 1 px/lane, 4 waves x 8 oc; LDS [8][10][11]
__global__ __launch_bounds__(256) void k_dec1(const float* __restrict__ q,
    const float* __restrict__ d1, const float* __restrict__ db1, float* __restrict__ out1)
{
  __shared__ float tile[8*110];
  const int b=blockIdx.z, r0=blockIdx.x*8, c0=blockIdx.y*8;
  const float* qp = q + (size_t)b*8*4096;
  for(int i=threadIdx.x;i<800;i+=256){
    int ic=i/100, rem=i-ic*100, r=rem/10, c=rem-r*10;
    int gr=r0+r-1, gc=c0+c-1;
    float v=0.f;
    if(gr>=0&&gr<64&&gc>=0&&gc<64) v=qp[ic*4096+gr*64+gc];
    tile[ic*110+r*11+c]=v;
  }
  __syncthreads();
  const int ocg=__builtin_amdgcn_readfirstlane((int)(threadIdx.x>>6));
  const int oc0=ocg*8;
  const int l=threadIdx.x&63, ry=l>>3, cx=l&7;
  float acc[8];
  #pragma unroll
  for(int o=0;o<8;o++) acc[o]=db1[oc0+o];
  #pragma unroll 2
  for(int ic=0;ic<8;ic++){
    float v[9];
    #pragma unroll
    for(int ky=0;ky<3;ky++)
      #pragma unroll
      for(int kx=0;kx<3;kx++)
        v[ky*3+kx]=tile[ic*110+(ry+ky)*11+cx+kx];
    #pragma unroll
    for(int o=0;o<8;o++){
      const float* wp=&d1[((oc0+o)*8+ic)*9];
      float s=acc[o];
      #pragma unroll
      for(int kk=0;kk<9;kk++) s=fmaf(v[kk],wp[kk],s);
      acc[o]=s;
    }
  }
  #pragma unroll
  for(int o=0;o<8;o++)
    out1[(((size_t)b*32+oc0+o)*64 + r0+ry)*64 + c0+cx]=acc[o];
}

// ---------------- K5: upsample2 + conv d2 (32->16,3x3,pad1) + gelu, at 128-res ----------------
// grid (8,8,32): 16x16 out tiles, 1 px/lane, wave = parity; LDS [32][10][11] = 14 KB
__global__ __launch_bounds__(256) void k_dec2(const float* __restrict__ out1,
    const float* __restrict__ wp4d2, const float* __restrict__ db2, float* __restrict__ out2)
{
  __shared__ float tile[32*110];
  const int b=blockIdx.z, y0=blockIdx.x*16, x0=blockIdx.y*16;
  const int sy0=(y0>>1)-1, sx0=(x0>>1)-1;
  const float* sp = out1 + (size_t)b*32*4096;
  for(int i=threadIdx.x;i<3200;i+=256){
    int ic=i/100, rem=i-ic*100, r=rem/10, c=rem-r*10;
    int gr=sy0+r, gc=sx0+c;
    float v=0.f;
    if(gr>=0&&gr<64&&gc>=0&&gc<64) v=sp[ic*4096+gr*64+gc];
    tile[ic*110+r*11+c]=v;
  }
  __syncthreads();
  const int par=__builtin_amdgcn_readfirstlane((int)(threadIdx.x>>6));
  const int py=par>>1, px=par&1;
  const int l=threadIdx.x&63, ry=l>>3, cx=l&7;
  const int byl=ry+py, bxl=cx+px;
  float acc[16];
  #pragma unroll
  for(int o=0;o<16;o++) acc[o]=db2[o];
  #pragma unroll 2
  for(int ic=0;ic<32;ic++){
    const float* tp=&tile[ic*110 + byl*11 + bxl];
    const float s00=tp[0], s01=tp[1], s10=tp[11], s11=tp[12];
    const float* wq = wp4d2 + (size_t)((par*32+ic)*16)*4;   // 64 uniform floats
    #pragma unroll
    for(int o=0;o<16;o++)
      acc[o]=fmaf(s00,wq[o*4],fmaf(s01,wq[o*4+1],fmaf(s10,wq[o*4+2],fmaf(s11,wq[o*4+3],acc[o]))));
  }
  const int Y=y0+2*ry+py, X=x0+2*cx+px;
  #pragma unroll
  for(int o=0;o<16;o++)
    out2[((size_t)b*16+o)*16384 + (size_t)Y*128 + X] = gelu_exact(acc[o]);
}

// ---------------- K6: upsample2 + conv d3 (16->1,3x3,pad1) + clip, at 256-res ----------------
__global__ __launch_bounds__(256) void k_dec3(const float* __restrict__ out2,
    const float* __restrict__ d3, const float* __restrict__ db3, float* __restrict__ y)
{
  __shared__ float tile[16*342];   // [ic][18][19] src at 128-res
  __shared__ float4 wp4[64];       // [par*16+ic]
  const int b=blockIdx.z, y0=blockIdx.x*32, x0=blockIdx.y*32;
  const int sy0=(y0>>1)-1, sx0=(x0>>1)-1;
  const float* sp = out2 + (size_t)b*16*16384;
  for(int i=threadIdx.x;i<16*324;i+=256){
    int ic=i/324, rem=i-ic*324, r=rem/18, c=rem-r*18;
    int gr=sy0+r, gc=sx0+c;
    float v=0.f;
    if(gr>=0&&gr<128&&gc>=0&&gc<128) v=sp[ic*16384+gr*128+gc];
    tile[ic*342+r*19+c]=v;
  }
  if(threadIdx.x<64){
    int par=threadIdx.x>>4, ic=threadIdx.x&15;
    int py=par>>1, px=par&1;
    const float* wg = d3 + ic*9;
    float a00=0.f,a01=0.f,a10=0.f,a11=0.f;
    #pragma unroll
    for(int ky=0;ky<3;ky++){
      int sy = py ? (ky>>1) : ((ky>0)?1:0);
      #pragma unroll
      for(int kx=0;kx<3;kx++){
        int sx = px ? (kx>>1) : ((kx>0)?1:0);
        float wv=wg[ky*3+kx];
        if(sy==0){ if(sx==0)a00+=wv; else a01+=wv; }
        else     { if(sx==0)a10+=wv; else a11+=wv; }
      }
    }
    wp4[threadIdx.x]=make_float4(a00,a01,a10,a11);
  }
  __syncthreads();
  const float bias=db3[0];
  const int par=__builtin_amdgcn_readfirstlane((int)(threadIdx.x>>6));
  const int py=par>>1, px=par&1;
  const int l=threadIdx.x&63, r0l=l>>4, cl=l&15;
  const int bxl=cl+px;
  float acc[4];
  #pragma unroll
  for(int a=0;a<4;a++) acc[a]=bias;
  #pragma unroll 2
  for(int ic=0;ic<16;ic++){
    const float4 wv=wp4[par*16+ic];
    #pragma unroll
    for(int a=0;a<4;a++){
      const int byl=r0l+4*a+py;
      const float* tp=&tile[ic*342 + byl*19 + bxl];
      acc[a]=fmaf(tp[0],wv.x,fmaf(tp[1],wv.y,fmaf(tp[19],wv.z,fmaf(tp[20],wv.w,acc[a]))));
    }
  }
  #pragma unroll
  for(int a=0;a<4;a++){
    const int yy=2*(r0l+4*a)+py, xx=2*cl+px;
    float v=fminf(fmaxf(acc[a],-1.0f),1.0f);
    y[(size_t)b*65536 + (size_t)(y0+yy)*256 + (x0+xx)] = v;
  }
}

extern "C" void kernel_launch(void* const* d_in, const int* in_sizes, int n_in,
                              void* d_out, int out_size, void* d_ws, size_t ws_size,
                              hipStream_t stream)
{
  const float* x  =(const float*)d_in[0];
  const float* w1 =(const float*)d_in[1];
  const float* b1 =(const float*)d_in[2];
  const float* w2 =(const float*)d_in[3];
  const float* b2 =(const float*)d_in[4];
  const float* w3 =(const float*)d_in[5];
  const float* b3 =(const float*)d_in[6];
  const float* d1 =(const float*)d_in[7];
  const float* db1=(const float*)d_in[8];
  const float* d2 =(const float*)d_in[9];
  const float* db2=(const float*)d_in[10];
  const float* d3 =(const float*)d_in[11];
  const float* db3=(const float*)d_in[12];
  float* out=(float*)d_out;
  float* ws =(float*)d_ws;
  // ws layout (floats):
  // h1[8388608] | h2[4194304] | qb[1048576] | st[256] | avgp[262144] | ec[2048]
  // | wp4d2[8192] | avgs[512]
  // Aliases (stream-order disjoint):
  //   w2t (4608 fl) = head of avgp   (prep->conv2, then lfq overwrites)
  //   pb  (16384 doubles = 128KB) = qb region (conv2->stats2, then lfq writes qb)
  //   out1 = h2 (dead after lfq) ; out2 = h1 (dead after conv2)
  float* h1   = ws;
  float* h2   = ws + 8388608;
  float* qb   = ws + 12582912;
  float* st   = ws + 13631488;
  float* avgp = ws + 13631744;
  float* ec   = ws + 13893888;
  float* w2t  = avgp;
  float* wp4d2= ws + 13895936;
  float* avgs = ws + 13904128;
  double* pb  = (double*)qb;
  float* out1 = h2;
  float* out2 = h1;

  k_prep  <<<dim3(8),256,0,stream>>>(w2,d2,w2t,wp4d2);
  k_conv1 <<<dim3(8,8,32),256,0,stream>>>(x,w1,b1,h1);
  k_conv2 <<<dim3(8,8,32),256,0,stream>>>(h1,w2t,b2,h2,pb);
  k_stats2<<<dim3(128),64,0,stream>>>(pb,st);
  k_lfq   <<<dim3(512),256,0,stream>>>(h2,st,w3,b3,qb,out+2097152,avgp,ec);
  k_red   <<<dim3(32),256,0,stream>>>(avgp,avgs);
  k_final <<<dim3(1),256,0,stream>>>(avgs,ec,out+2359296);
  k_dec1  <<<dim3(8,8,32),256,0,stream>>>(qb,d1,db1,out1);
  k_dec2  <<<dim3(8,8,32),256,0,stream>>>(out1,wp4d2,db2,out2);
  k_dec3  <<<dim3(8,8,32),256,0,stream>>>(out2,d3,db3,out);
}

// Round 7
// 192.198 us; speedup vs baseline: 13.5864x; 1.0526x over previous
//
#include <hip/hip_runtime.h>
#include <hip/hip_bf16.h>
#include <math.h>

#define DEV __device__ __forceinline__

DEV float gelu_exact(float x){ return 0.5f*x*(1.0f + erff(x*0.70710678118654752f)); }

// ---------------- K1: conv1(1->16,3x3,pad1) + maxpool2 + gelu  (+ fused weight prep) ----------------
// XCD-locality: x-tile = blockIdx.y. Blocks (0,0,z<8) additionally build w2t/wp4d2
// (consumed by conv2/dec2 which launch after conv1 completes).
__global__ __launch_bounds__(256) void k_conv1(const float* __restrict__ x,
    const float* __restrict__ w1, const float* __restrict__ b1,
    float* __restrict__ h1,
    const float* __restrict__ w2, const float* __restrict__ d2,
    float* __restrict__ w2t, float* __restrict__ wp4d2)
{
  __shared__ float sE[34*19], sO[34*19];
  const int b = blockIdx.z;
  const int r0 = blockIdx.x*32, c0 = blockIdx.y*32;
  const float* xp = x + (size_t)b*65536;
  for(int i=threadIdx.x;i<34*34;i+=256){
    int r=i/34, c=i-r*34;
    int gr=r0+r-1, gc=c0+c-1;
    float v=0.f;
    if(gr>=0 && gr<256 && gc>=0 && gc<256) v = xp[gr*256+gc];
    if(c&1) sO[r*19+(c>>1)]=v; else sE[r*19+(c>>1)]=v;
  }
  __syncthreads();
  const int tx=threadIdx.x&15, ty=threadIdx.x>>4;
  const int base = 2*ty*19 + tx;
  float in[4][4];
  #pragma unroll
  for(int r=0;r<4;r++){
    in[r][0]=sE[base+r*19]; in[r][1]=sO[base+r*19];
    in[r][2]=sE[base+r*19+1]; in[r][3]=sO[base+r*19+1];
  }
  const int py = blockIdx.x*16+ty, px = blockIdx.y*16+tx;
  float* op = h1 + ((size_t)b*16)*16384 + py*128 + px;
  #pragma unroll
  for(int ch=0;ch<16;ch++){
    float m=-1e30f;
    #pragma unroll
    for(int pr=0;pr<2;pr++)
      #pragma unroll
      for(int pc=0;pc<2;pc++){
        float a=0.f;
        #pragma unroll
        for(int ky=0;ky<3;ky++)
          #pragma unroll
          for(int kx=0;kx<3;kx++)
            a = fmaf(in[pr+ky][pc+kx], w1[ch*9+ky*3+kx], a);
        m = fmaxf(m,a);
      }
    op[(size_t)ch*16384] = gelu_exact(m + b1[ch]);
  }
  // ---- fused prep (8 blocks worth of work) ----
  if(blockIdx.x==0 && blockIdx.y==0 && b<8){
    const int gid = b*256 + threadIdx.x;
    for(int i=gid;i<4608;i+=2048){
      int oc=i/144, rem=i-oc*144, ic=rem/9, k=rem-ic*9;
      w2t[(ic*32+oc)*9+k]=w2[i];
    }
    for(int i=gid;i<2048;i+=2048){
      int par=i>>9, ic=(i>>4)&31, oc=i&15;
      int pyp=par>>1, pxp=par&1;
      const float* wg = d2 + ((size_t)oc*32+ic)*9;
      float a00=0.f,a01=0.f,a10=0.f,a11=0.f;
      #pragma unroll
      for(int ky=0;ky<3;ky++){
        int sy = pyp ? (ky>>1) : ((ky>0)?1:0);
        #pragma unroll
        for(int kx=0;kx<3;kx++){
          int sx = pxp ? (kx>>1) : ((kx>0)?1:0);
          float wv=wg[ky*3+kx];
          if(sy==0){ if(sx==0)a00+=wv; else a01+=wv; }
          else     { if(sx==0)a10+=wv; else a11+=wv; }
        }
      }
      float* dst=wp4d2+(size_t)i*4;
      dst[0]=a00; dst[1]=a01; dst[2]=a10; dst[3]=a11;
    }
  }
}

// ---------------- K2: conv2(16->32,3x3,pad1) + maxpool2 + groupnorm partials ----------------
// Double-buffered, register-staged pipeline: half-1 global loads issued before
// the first barrier; 2 barriers/block total (was 4). LDS 2x11.5KB.
__global__ __launch_bounds__(256) void k_conv2(const float* __restrict__ h1,
    const float* __restrict__ w2t, const float* __restrict__ b2,
    float* __restrict__ h2, double* __restrict__ pb)
{
  __shared__ __align__(16) float t2[2][8*360];   // [buf][ic][18][20]
  const int b=blockIdx.z;
  const int r0=blockIdx.x*16, c0=blockIdx.y*16;  // unpooled origin (128-res)
  const float* hp = h1 + (size_t)b*16*16384;
  const int t=threadIdx.x;
  // staging descriptors, computed once (slots 0..4 full, slot 5: t<16)
  int lofs[6]; int gof[6]; bool ok0[6], ok1[6];
  #pragma unroll
  for(int s=0;s<6;s++){
    int idx=s*256+t;
    int ic=idx/162, rem=idx-162*ic, lr=rem/9, jp=rem-9*lr;
    int gr=r0+lr-1, gc=c0+2*jp-1;
    bool rok = (gr>=0) && (gr<128);
    ok0[s] = rok && (gc>=0);
    ok1[s] = rok && (gc+1<128);
    lofs[s]= ic*360+lr*20+2*jp;
    gof[s] = ic*16384 + gr*128 + gc;
  }
  float a0[6], a1[6], c0r[6], c1r[6];
  // load half 0
  #pragma unroll
  for(int s=0;s<6;s++){
    if(s<5 || t<16){
      a0[s] = ok0[s] ? hp[gof[s]]   : 0.f;
      a1[s] = ok1[s] ? hp[gof[s]+1] : 0.f;
    }
  }
  // write half 0 to buf0
  #pragma unroll
  for(int s=0;s<6;s++)
    if(s<5 || t<16) *(float2*)&t2[0][lofs[s]]=make_float2(a0[s],a1[s]);
  // issue half 1 loads (latency hides under barrier + compute0)
  const float* hp1 = hp + 8*16384;
  #pragma unroll
  for(int s=0;s<6;s++){
    if(s<5 || t<16){
      c0r[s] = ok0[s] ? hp1[gof[s]]   : 0.f;
      c1r[s] = ok1[s] ? hp1[gof[s]+1] : 0.f;
    }
  }
  __syncthreads();

  const int pos=t&63;
  const int ocg=__builtin_amdgcn_readfirstlane((int)(t>>6));
  const int oc0=ocg*8;
  const int pyl=pos>>3, pxl=pos&7;
  const int base0 = 2*pyl*20 + 2*pxl;
  float acc[8][4];
  #pragma unroll
  for(int o=0;o<8;o++)
    #pragma unroll
    for(int j=0;j<4;j++) acc[o][j]=0.f;

  // compute half 0
  #pragma unroll 4
  for(int ic=0;ic<8;ic++){
    float in[4][4];
    #pragma unroll
    for(int r=0;r<4;r++){
      float2 a=*(const float2*)&t2[0][ic*360 + base0 + r*20];
      float2 c=*(const float2*)&t2[0][ic*360 + base0 + r*20 + 2];
      in[r][0]=a.x; in[r][1]=a.y; in[r][2]=c.x; in[r][3]=c.y;
    }
    const float* wp = w2t + (ic*32+oc0)*9;
    #pragma unroll
    for(int o=0;o<8;o++){
      #pragma unroll
      for(int pr=0;pr<2;pr++)
        #pragma unroll
        for(int pc=0;pc<2;pc++){
          float s=acc[o][pr*2+pc];
          #pragma unroll
          for(int ky=0;ky<3;ky++)
            #pragma unroll
            for(int kx=0;kx<3;kx++)
              s=fmaf(in[pr+ky][pc+kx], wp[o*9+ky*3+kx], s);
          acc[o][pr*2+pc]=s;
        }
    }
  }
  // write half 1 to buf1 (loads already in flight)
  #pragma unroll
  for(int s=0;s<6;s++)
    if(s<5 || t<16) *(float2*)&t2[1][lofs[s]]=make_float2(c0r[s],c1r[s]);
  __syncthreads();
  // compute half 1
  #pragma unroll 4
  for(int ic=0;ic<8;ic++){
    float in[4][4];
    #pragma unroll
    for(int r=0;r<4;r++){
      float2 a=*(const float2*)&t2[1][ic*360 + base0 + r*20];
      float2 c=*(const float2*)&t2[1][ic*360 + base0 + r*20 + 2];
      in[r][0]=a.x; in[r][1]=a.y; in[r][2]=c.x; in[r][3]=c.y;
    }
    const float* wp = w2t + ((8+ic)*32+oc0)*9;
    #pragma unroll
    for(int o=0;o<8;o++){
      #pragma unroll
      for(int pr=0;pr<2;pr++)
        #pragma unroll
        for(int pc=0;pc<2;pc++){
          float s=acc[o][pr*2+pc];
          #pragma unroll
          for(int ky=0;ky<3;ky++)
            #pragma unroll
            for(int kx=0;kx<3;kx++)
              s=fmaf(in[pr+ky][pc+kx], wp[o*9+ky*3+kx], s);
          acc[o][pr*2+pc]=s;
        }
    }
  }

  const int py=blockIdx.x*8+pyl, px=blockIdx.y*8+pxl;
  double s=0.0, s2=0.0;
  #pragma unroll
  for(int o=0;o<8;o++){
    const int oc=oc0+o;
    float m=fmaxf(fmaxf(acc[o][0],acc[o][1]),fmaxf(acc[o][2],acc[o][3]));
    float hv=m+b2[oc];
    h2[(((size_t)b*32+oc)*64+py)*64+px]=hv;
    s += (double)hv; s2 += (double)hv*(double)hv;
  }
  #pragma unroll
  for(int off=32;off;off>>=1){
    s  += __shfl_xor(s,  off, 64);
    s2 += __shfl_xor(s2, off, 64);
  }
  if(pos==0){
    const int bidx = blockIdx.x*8 + blockIdx.y;
    double* p = pb + (((size_t)b*4+ocg)*64 + bidx)*2;
    p[0]=s; p[1]=s2;
  }
}

// ---------------- K2b: stats finalize (128 groups, f64, deterministic) ----------------
__global__ __launch_bounds__(64) void k_stats2(const double* __restrict__ pb,
                                               float* __restrict__ stats)
{
  const int bg=blockIdx.x, t=threadIdx.x;
  double s = pb[((size_t)bg*64+t)*2], s2 = pb[((size_t)bg*64+t)*2+1];
  #pragma unroll
  for(int off=32;off;off>>=1){
    s  += __shfl_xor(s,  off, 64);
    s2 += __shfl_xor(s2, off, 64);
  }
  if(t==0){
    double mu=s/32768.0;
    double var=s2/32768.0 - mu*mu;
    stats[bg]=(float)mu;
    stats[128+bg]=(float)(1.0/sqrt(var+1e-5));
  }
}

// ---------------- K3: groupnorm-apply + 1x1 conv + residual LFQ ----------------
// Phase-2: tabL/tabH [16][260] float4 reads (16B-aligned rows; 2-way/broadcast banks).
__global__ __launch_bounds__(256) void k_lfq(const float* __restrict__ h2,
    const float* __restrict__ stats, const float* __restrict__ w3, const float* __restrict__ b3,
    float* __restrict__ qout, float* __restrict__ idxout,
    float* __restrict__ avgp, float* __restrict__ ec)
{
  __shared__ __align__(16) float tabL[16*260];
  __shared__ __align__(16) float tabH[16*260];
  const int blk=blockIdx.x;
  const int b=blk>>4;
  const int t=threadIdx.x;
  const int h=(blk&15)*4 + (t>>6);
  const int w=t&63;
  float mu[4], rs[4];
  #pragma unroll
  for(int g=0;g<4;g++){ mu[g]=stats[b*4+g]; rs[g]=stats[128+b*4+g]; }
  const float* hp = h2 + (size_t)b*131072 + h*64 + w;
  float z[8];
  #pragma unroll
  for(int d=0;d<8;d++) z[d]=b3[d];
  #pragma unroll
  for(int c=0;c<32;c++){
    float xn=(hp[(size_t)c*4096]-mu[c>>3])*rs[c>>3];
    #pragma unroll
    for(int d=0;d<8;d++) z[d]=fmaf(xn, w3[d*32+c], z[d]);
  }
  float r[8], qsum[8];
  #pragma unroll
  for(int d=0;d<8;d++){ r[d]=z[d]; qsum[d]=0.f; }
  float entk[2], comk[2];
  #pragma unroll
  for(int k=0;k<2;k++){
    int idx=0; float ent=0.f, com=0.f;
    float pb0[8], pb1[8];
    #pragma unroll
    for(int d=0;d<8;d++){
      float rv=r[d];
      bool pos = rv>0.f;
      float sgn = pos?1.f:-1.f;
      idx |= (pos?1:0)<<d;
      float dd=rv-sgn; com=fmaf(dd,dd,com);
      float a=400.f*fabsf(rv);
      float e=__expf(-a);
      float p=1.f/(1.f+e);
      ent += a - p*a - __logf(p);
      float pm=p, pq=1.f-p;
      pb1[d]=pos?pm:pq;
      pb0[d]=pos?pq:pm;
      qsum[d]+=sgn;
      r[d]=rv-sgn;
    }
    float lo[16], hi[16];
    lo[0]=pb0[0]; lo[1]=pb1[0];
    lo[2]=lo[0]*pb1[1]; lo[3]=lo[1]*pb1[1]; lo[0]*=pb0[1]; lo[1]*=pb0[1];
    lo[4]=lo[0]*pb1[2]; lo[5]=lo[1]*pb1[2]; lo[6]=lo[2]*pb1[2]; lo[7]=lo[3]*pb1[2];
    lo[0]*=pb0[2]; lo[1]*=pb0[2]; lo[2]*=pb0[2]; lo[3]*=pb0[2];
    lo[8]=lo[0]*pb1[3]; lo[9]=lo[1]*pb1[3]; lo[10]=lo[2]*pb1[3]; lo[11]=lo[3]*pb1[3];
    lo[12]=lo[4]*pb1[3]; lo[13]=lo[5]*pb1[3]; lo[14]=lo[6]*pb1[3]; lo[15]=lo[7]*pb1[3];
    lo[0]*=pb0[3]; lo[1]*=pb0[3]; lo[2]*=pb0[3]; lo[3]*=pb0[3];
    lo[4]*=pb0[3]; lo[5]*=pb0[3]; lo[6]*=pb0[3]; lo[7]*=pb0[3];
    hi[0]=pb0[4]; hi[1]=pb1[4];
    hi[2]=hi[0]*pb1[5]; hi[3]=hi[1]*pb1[5]; hi[0]*=pb0[5]; hi[1]*=pb0[5];
    hi[4]=hi[0]*pb1[6]; hi[5]=hi[1]*pb1[6]; hi[6]=hi[2]*pb1[6]; hi[7]=hi[3]*pb1[6];
    hi[0]*=pb0[6]; hi[1]*=pb0[6]; hi[2]*=pb0[6]; hi[3]*=pb0[6];
    hi[8]=hi[0]*pb1[7]; hi[9]=hi[1]*pb1[7]; hi[10]=hi[2]*pb1[7]; hi[11]=hi[3]*pb1[7];
    hi[12]=hi[4]*pb1[7]; hi[13]=hi[5]*pb1[7]; hi[14]=hi[6]*pb1[7]; hi[15]=hi[7]*pb1[7];
    hi[0]*=pb0[7]; hi[1]*=pb0[7]; hi[2]*=pb0[7]; hi[3]*=pb0[7];
    hi[4]*=pb0[7]; hi[5]*=pb0[7]; hi[6]*=pb0[7]; hi[7]*=pb0[7];
    #pragma unroll
    for(int m=0;m<16;m++){ tabL[m*260+t]=lo[m]; tabH[m*260+t]=hi[m]; }
    __syncthreads();
    float accp=0.f, accq=0.f;
    const int jl=t&15, jh=t>>4;
    const float* Lp=&tabL[jl*260];
    const float* Hp=&tabH[jh*260];
    #pragma unroll 4
    for(int q4=0;q4<64;q4++){
      float4 L=*(const float4*)&Lp[4*q4];
      float4 H=*(const float4*)&Hp[4*q4];
      accp=fmaf(L.x,H.x,accp); accq=fmaf(L.y,H.y,accq);
      accp=fmaf(L.z,H.z,accp); accq=fmaf(L.w,H.w,accq);
    }
    avgp[((size_t)k*512+blk)*256+t]=accp+accq;
    __syncthreads();
    entk[k]=ent; comk[k]=com;
    idxout[((size_t)(b*64+h)*64+w)*2+k]=(float)idx;
  }
  #pragma unroll
  for(int d=0;d<8;d++)
    qout[(((size_t)b*8+d)*64+h)*64+w]=qsum[d];
  tabL[t]=entk[0]; tabL[256+t]=entk[1]; tabL[512+t]=comk[0]; tabL[768+t]=comk[1];
  __syncthreads();
  for(int st=128;st>0;st>>=1){
    if(t<st){ tabL[t]+=tabL[t+st]; tabL[256+t]+=tabL[256+t+st];
              tabL[512+t]+=tabL[512+t+st]; tabL[768+t]+=tabL[768+t+st]; }
    __syncthreads();
  }
  if(t==0){ ec[blk*4+0]=tabL[0]; ec[blk*4+1]=tabL[256]; ec[blk*4+2]=tabL[512]; ec[blk*4+3]=tabL[768]; }
}

// ---------------- K3r: parallel avgp reduction (32 blocks) ----------------
__global__ __launch_bounds__(256) void k_red(const float* __restrict__ avgp,
    float* __restrict__ avgs)
{
  const int k=blockIdx.x>>4, c0=(blockIdx.x&15)*16;
  const int col=threadIdx.x&15, rg=threadIdx.x>>4;
  float s=0.f;
  for(int j=0;j<32;j++){
    int blk=rg+16*j;
    s+=avgp[((size_t)k*512+blk)*256+c0+col];
  }
  __shared__ float red[256];
  red[threadIdx.x]=s; __syncthreads();
  for(int st=128;st>=16;st>>=1){
    if(threadIdx.x<st) red[threadIdx.x]+=red[threadIdx.x+st];
    __syncthreads();
  }
  if(threadIdx.x<16) avgs[k*256+c0+threadIdx.x]=red[threadIdx.x];
}

// ---------------- K3b: final aux (1 block, deterministic, f64) ----------------
__global__ __launch_bounds__(256) void k_final(const float* __restrict__ avgs,
    const float* __restrict__ ec, float* __restrict__ auxout)
{
  __shared__ double red[256];
  const int t=threadIdx.x;
  double cb=0.0;
  #pragma unroll
  for(int k=0;k<2;k++){
    double ap=(double)avgs[k*256+t]*(1.0/131072.0);
    cb += -(ap*log(ap+1e-10));
  }
  red[t]=cb; __syncthreads();
  for(int st=128;st>0;st>>=1){ if(t<st) red[t]+=red[t+st]; __syncthreads(); }
  double CB=red[0]; __syncthreads();
  double e=0.0,c=0.0;
  for(int blk=t;blk<512;blk+=256){
    e += (double)ec[blk*4+0]+(double)ec[blk*4+1];
    c += (double)ec[blk*4+2]+(double)ec[blk*4+3];
  }
  red[t]=e; __syncthreads();
  for(int st=128;st>0;st>>=1){ if(t<st) red[t]+=red[t+st]; __syncthreads(); }
  double E=red[0]; __syncthreads();
  red[t]=c; __syncthreads();
  for(int st=128;st>0;st>>=1){ if(t<st) red[t]+=red[t+st]; __syncthreads(); }
  if(t==0){
    double C=red[0];
    double aux = 0.1*(E*(1.0/131072.0) - CB) + C*(1.0/1048576.0);
    auxout[0]=(float)aux;
  }
}

// ---------------- K4: decoder conv d1 (8->32, 3x3, pad1) on 64x64 ----------------
// grid (8,8,32): 8x8 tiles, 1 px/lane, 4 waves x 8 oc; LDS [8][10][11]
__global__ __launch_bounds__(256) void k_dec1(const float* __restrict__ q,
    const float* __restrict__ d1, const float* __restrict__ db1, float* __restrict__ out1)
{
  __shared__ float tile[8*110];
  const int b=blockIdx.z, r0=blockIdx.x*8, c0=blockIdx.y*8;
  const float* qp = q + (size_t)b*8*4096;
  for(int i=threadIdx.x;i<800;i+=256){
    int ic=i/100, rem=i-ic*100, r=rem/10, c=rem-r*10;
    int gr=r0+r-1, gc=c0+c-1;
    float v=0.f;
    if(gr>=0&&gr<64&&gc>=0&&gc<64) v=qp[ic*4096+gr*64+gc];
    tile[ic*110+r*11+c]=v;
  }
  __syncthreads();
  const int ocg=__builtin_amdgcn_readfirstlane((int)(threadIdx.x>>6));
  const int oc0=ocg*8;
  const int l=threadIdx.x&63, ry=l>>3, cx=l&7;
  float acc[8];
  #pragma unroll
  for(int o=0;o<8;o++) acc[o]=db1[oc0+o];
  #pragma unroll 2
  for(int ic=0;ic<8;ic++){
    float v[9];
    #pragma unroll
    for(int ky=0;ky<3;ky++)
      #pragma unroll
      for(int kx=0;kx<3;kx++)
        v[ky*3+kx]=tile[ic*110+(ry+ky)*11+cx+kx];
    #pragma unroll
    for(int o=0;o<8;o++){
      const float* wp=&d1[((oc0+o)*8+ic)*9];
      float s=acc[o];
      #pragma unroll
      for(int kk=0;kk<9;kk++) s=fmaf(v[kk],wp[kk],s);
      acc[o]=s;
    }
  }
  #pragma unroll
  for(int o=0;o<8;o++)
    out1[(((size_t)b*32+oc0+o)*64 + r0+ry)*64 + c0+cx]=acc[o];
}

// ---------------- K5: upsample2 + conv d2 (32->16,3x3,pad1) + gelu, at 128-res ----------------
// grid (8,8,32): 16x16 out tiles, 1 px/lane, wave = parity; LDS [32][10][11]
__global__ __launch_bounds__(256) void k_dec2(const float* __restrict__ out1,
    const float* __restrict__ wp4d2, const float* __restrict__ db2, float* __restrict__ out2)
{
  __shared__ float tile[32*110];
  const int b=blockIdx.z, y0=blockIdx.x*16, x0=blockIdx.y*16;
  const int sy0=(y0>>1)-1, sx0=(x0>>1)-1;
  const float* sp = out1 + (size_t)b*32*4096;
  for(int i=threadIdx.x;i<3200;i+=256){
    int ic=i/100, rem=i-ic*100, r=rem/10, c=rem-r*10;
    int gr=sy0+r, gc=sx0+c;
    float v=0.f;
    if(gr>=0&&gr<64&&gc>=0&&gc<64) v=sp[ic*4096+gr*64+gc];
    tile[ic*110+r*11+c]=v;
  }
  __syncthreads();
  const int par=__builtin_amdgcn_readfirstlane((int)(threadIdx.x>>6));
  const int py=par>>1, px=par&1;
  const int l=threadIdx.x&63, ry=l>>3, cx=l&7;
  const int byl=ry+py, bxl=cx+px;
  float acc[16];
  #pragma unroll
  for(int o=0;o<16;o++) acc[o]=db2[o];
  #pragma unroll 2
  for(int ic=0;ic<32;ic++){
    const float* tp=&tile[ic*110 + byl*11 + bxl];
    const float s00=tp[0], s01=tp[1], s10=tp[11], s11=tp[12];
    const float* wq = wp4d2 + (size_t)((par*32+ic)*16)*4;   // 64 uniform floats
    #pragma unroll
    for(int o=0;o<16;o++)
      acc[o]=fmaf(s00,wq[o*4],fmaf(s01,wq[o*4+1],fmaf(s10,wq[o*4+2],fmaf(s11,wq[o*4+3],acc[o]))));
  }
  const int Y=y0+2*ry+py, X=x0+2*cx+px;
  #pragma unroll
  for(int o=0;o<16;o++)
    out2[((size_t)b*16+o)*16384 + (size_t)Y*128 + X] = gelu_exact(acc[o]);
}

// ---------------- K6: upsample2 + conv d3 (16->1,3x3,pad1) + clip, at 256-res ----------------
__global__ __launch_bounds__(256) void k_dec3(const float* __restrict__ out2,
    const float* __restrict__ d3, const float* __restrict__ db3, float* __restrict__ y)
{
  __shared__ float tile[16*342];   // [ic][18][19] src at 128-res
  __shared__ float4 wp4[64];       // [par*16+ic]
  const int b=blockIdx.z, y0=blockIdx.x*32, x0=blockIdx.y*32;
  const int sy0=(y0>>1)-1, sx0=(x0>>1)-1;
  const float* sp = out2 + (size_t)b*16*16384;
  for(int i=threadIdx.x;i<16*324;i+=256){
    int ic=i/324, rem=i-ic*324, r=rem/18, c=rem-r*18;
    int gr=sy0+r, gc=sx0+c;
    float v=0.f;
    if(gr>=0&&gr<128&&gc>=0&&gc<128) v=sp[ic*16384+gr*128+gc];
    tile[ic*342+r*19+c]=v;
  }
  if(threadIdx.x<64){
    int par=threadIdx.x>>4, ic=threadIdx.x&15;
    int py=par>>1, px=par&1;
    const float* wg = d3 + ic*9;
    float a00=0.f,a01=0.f,a10=0.f,a11=0.f;
    #pragma unroll
    for(int ky=0;ky<3;ky++){
      int sy = py ? (ky>>1) : ((ky>0)?1:0);
      #pragma unroll
      for(int kx=0;kx<3;kx++){
        int sx = px ? (kx>>1) : ((kx>0)?1:0);
        float wv=wg[ky*3+kx];
        if(sy==0){ if(sx==0)a00+=wv; else a01+=wv; }
        else     { if(sx==0)a10+=wv; else a11+=wv; }
      }
    }
    wp4[threadIdx.x]=make_float4(a00,a01,a10,a11);
  }
  __syncthreads();
  const float bias=db3[0];
  const int par=__builtin_amdgcn_readfirstlane((int)(threadIdx.x>>6));
  const int py=par>>1, px=par&1;
  const int l=threadIdx.x&63, r0l=l>>4, cl=l&15;
  const int bxl=cl+px;
  float acc[4];
  #pragma unroll
  for(int a=0;a<4;a++) acc[a]=bias;
  #pragma unroll 2
  for(int ic=0;ic<16;ic++){
    const float4 wv=wp4[par*16+ic];
    #pragma unroll
    for(int a=0;a<4;a++){
      const int byl=r0l+4*a+py;
      const float* tp=&tile[ic*342 + byl*19 + bxl];
      acc[a]=fmaf(tp[0],wv.x,fmaf(tp[1],wv.y,fmaf(tp[19],wv.z,fmaf(tp[20],wv.w,acc[a]))));
    }
  }
  #pragma unroll
  for(int a=0;a<4;a++){
    const int yy=2*(r0l+4*a)+py, xx=2*cl+px;
    float v=fminf(fmaxf(acc[a],-1.0f),1.0f);
    y[(size_t)b*65536 + (size_t)(y0+yy)*256 + (x0+xx)] = v;
  }
}

extern "C" void kernel_launch(void* const* d_in, const int* in_sizes, int n_in,
                              void* d_out, int out_size, void* d_ws, size_t ws_size,
                              hipStream_t stream)
{
  const float* x  =(const float*)d_in[0];
  const float* w1 =(const float*)d_in[1];
  const float* b1 =(const float*)d_in[2];
  const float* w2 =(const float*)d_in[3];
  const float* b2 =(const float*)d_in[4];
  const float* w3 =(const float*)d_in[5];
  const float* b3 =(const float*)d_in[6];
  const float* d1 =(const float*)d_in[7];
  const float* db1=(const float*)d_in[8];
  const float* d2 =(const float*)d_in[9];
  const float* db2=(const float*)d_in[10];
  const float* d3 =(const float*)d_in[11];
  const float* db3=(const float*)d_in[12];
  float* out=(float*)d_out;
  float* ws =(float*)d_ws;
  // ws layout (floats):
  // h1[8388608] | h2[4194304] | qb[1048576] | st[256] | avgp[262144] | ec[2048]
  // | wp4d2[8192] | avgs[512]
  // Aliases (stream-order disjoint):
  //   w2t (4608 fl) = head of avgp   (conv1-prep -> conv2, then lfq overwrites)
  //   pb  (16384 doubles) = qb region (conv2 -> stats2, then lfq writes qb)
  //   out1 = h2 (dead after lfq) ; out2 = h1 (dead after conv2)
  float* h1   = ws;
  float* h2   = ws + 8388608;
  float* qb   = ws + 12582912;
  float* st   = ws + 13631488;
  float* avgp = ws + 13631744;
  float* ec   = ws + 13893888;
  float* w2t  = avgp;
  float* wp4d2= ws + 13895936;
  float* avgs = ws + 13904128;
  double* pb  = (double*)qb;
  float* out1 = h2;
  float* out2 = h1;

  k_conv1 <<<dim3(8,8,32),256,0,stream>>>(x,w1,b1,h1,w2,d2,w2t,wp4d2);
  k_conv2 <<<dim3(8,8,32),256,0,stream>>>(h1,w2t,b2,h2,pb);
  k_stats2<<<dim3(128),64,0,stream>>>(pb,st);
  k_lfq   <<<dim3(512),256,0,stream>>>(h2,st,w3,b3,qb,out+2097152,avgp,ec);
  k_red   <<<dim3(32),256,0,stream>>>(avgp,avgs);
  k_final <<<dim3(1),256,0,stream>>>(avgs,ec,out+2359296);
  k_dec1  <<<dim3(8,8,32),256,0,stream>>>(qb,d1,db1,out1);
  k_dec2  <<<dim3(8,8,32),256,0,stream>>>(out1,wp4d2,db2,out2);
  k_dec3  <<<dim3(8,8,32),256,0,stream>>>(out2,d3,db3,out);
}